// Round 2
// baseline (883.783 us; speedup 1.0000x reference)
//
#include <hip/hip_runtime.h>
#include <hip/hip_bf16.h>
#include <math.h>
#include <stdint.h>

// Problem constants (B, L, H, D) = (4, 2048, 8, 64); FACTOR=5 => U_part = u = 40.
static constexpr int BB = 4;
static constexpr int LL = 2048;
static constexpr int HH = 8;
static constexpr int DD = 64;
static constexpr int UU = 40;   // top-k count
static constexpr int NSAMP = 40; // sampled keys per query
static constexpr int BHL = BB * HH * LL;       // 65536
static constexpr int NIDX = LL * NSAMP;        // 81920

// ---------------- Threefry-2x32 (JAX-compatible, 20 rounds) ----------------
__device__ __forceinline__ uint32_t rotl32(uint32_t x, uint32_t n) {
  return (x << n) | (x >> (32u - n));
}

__device__ __forceinline__ void tf2x32(uint32_t k0, uint32_t k1,
                                       uint32_t x0, uint32_t x1,
                                       uint32_t& o0, uint32_t& o1) {
  uint32_t ks[3] = {k0, k1, k0 ^ k1 ^ 0x1BD11BDAu};
  x0 += ks[0];
  x1 += ks[1];
  const uint32_t rotA[4] = {13u, 15u, 26u, 6u};
  const uint32_t rotB[4] = {17u, 29u, 16u, 24u};
#pragma unroll
  for (int i = 0; i < 5; ++i) {
    const uint32_t* r = (i & 1) ? rotB : rotA;
#pragma unroll
    for (int j = 0; j < 4; ++j) {
      x0 += x1;
      x1 = rotl32(x1, r[j]);
      x1 ^= x0;
    }
    x0 += ks[(i + 1) % 3];
    x1 += ks[(i + 2) % 3] + (uint32_t)(i + 1);
  }
  o0 = x0;
  o1 = x1;
}

// index_sample = randint(split(key(42))[1], (2048,40), 0, 2048)
// jax_threefry_partitionable=True (default, jax>=0.5):
//   split foldlike: k2 = both words of threefry((0,42), x0=0, x1=1)
//   random_bits(32): per element i, hash counter (hi=0, lo=i); bits = o0 ^ o1
//   span=2048 divides 2^16 => multiplier term vanishes => idx = bits % 2048
__global__ void k_build_idx(int* __restrict__ idx) {
  int i = blockIdx.x * 256 + threadIdx.x;
  if (i >= NIDX) return;
  uint32_t ka, kb;
  tf2x32(0u, 42u, 0u, 1u, ka, kb);  // split(key(42)) -> second subkey
  uint32_t o0, o1;
  tf2x32(ka, kb, 0u, (uint32_t)i, o0, o1);
  idx[i] = (int)((o0 ^ o1) & 2047u);
}

// M[b,h,q] = max_s(QK_sample) - mean_s(QK_sample), fp64 accumulation.
// One wave (64 lanes) per (b,h,q); lane = d.
__global__ void k_scores_M(const float* __restrict__ q, const float* __restrict__ k,
                           const int* __restrict__ idx, double* __restrict__ M) {
  int w = (blockIdx.x * blockDim.x + threadIdx.x) >> 6;  // wave id
  int lane = threadIdx.x & 63;
  if (w >= BHL) return;
  int qq = w & (LL - 1);
  int h = (w >> 11) & (HH - 1);
  int b = w >> 14;
  float qv = q[(((size_t)b * LL + qq) * HH + h) * DD + lane];
  double mx = -1.0e300;
  double sm = 0.0;
  const int* row_idx = idx + qq * NSAMP;
#pragma unroll 4
  for (int s = 0; s < NSAMP; ++s) {
    int krow = row_idx[s];
    double val = (double)qv * (double)k[(((size_t)b * LL + krow) * HH + h) * DD + lane];
#pragma unroll
    for (int off = 32; off; off >>= 1) val += __shfl_xor(val, off);
    mx = fmax(mx, val);
    sm += val;
  }
  if (lane == 0) M[w] = mx - sm * (1.0 / (double)NSAMP);
}

// Top-40 indices per (b,h) with lax.top_k tie-breaking (lower index first).
__global__ void k_topk(const double* __restrict__ M, int* __restrict__ mtop) {
  __shared__ double sv[LL];
  __shared__ double rv[256];
  __shared__ int ri[256];
  int bh = blockIdx.x;
  int t = threadIdx.x;
  const double* m = M + (size_t)bh * LL;
  for (int i = t; i < LL; i += 256) sv[i] = m[i];
  __syncthreads();
  for (int it = 0; it < UU; ++it) {
    double best = -1.0e300;
    int bi = 1 << 30;
    for (int i = t; i < LL; i += 256) {
      double v = sv[i];
      if (v > best) { best = v; bi = i; }  // strided ascending -> lowest idx kept on tie
    }
    rv[t] = best;
    ri[t] = bi;
    __syncthreads();
    for (int off = 128; off; off >>= 1) {
      if (t < off) {
        if (rv[t + off] > rv[t] || (rv[t + off] == rv[t] && ri[t + off] < ri[t])) {
          rv[t] = rv[t + off];
          ri[t] = ri[t + off];
        }
      }
      __syncthreads();
    }
    if (t == 0) {
      mtop[bh * UU + it] = ri[0];
      sv[ri[0]] = -1.0e300;
    }
    __syncthreads();
  }
}

// V_mean[b,h,d] = mean over l of v[b,l,h,d]
__global__ void k_vmean(const float* __restrict__ v, float* __restrict__ vmean) {
  int t = blockIdx.x * 256 + threadIdx.x;  // 0..2047 = (b*H+h)*64 + d
  if (t >= BB * HH * DD) return;
  int d = t & 63;
  int bh = t >> 6;
  int b = bh >> 3;
  int h = bh & 7;
  const float* base = v + ((size_t)b * LL * HH + h) * DD + d;
  double s = 0.0;
  for (int l = 0; l < LL; ++l) s += (double)base[(size_t)l * HH * DD];
  vmean[t] = (float)(s * (1.0 / (double)LL));
}

// out[b,l,h,d] = vmean[b,h,d]
__global__ void k_fill(const float* __restrict__ vmean, float* __restrict__ out) {
  int i = blockIdx.x * 256 + threadIdx.x;
  int d = i & 63;
  int h = (i >> 6) & 7;
  int b = i >> 20;
  out[i] = vmean[(((b << 3) + h) << 6) | d];
}

// Full softmax attention for the selected queries; scatter into out.
__global__ void k_attn(const float* __restrict__ q, const float* __restrict__ k,
                       const float* __restrict__ v, const int* __restrict__ mtop,
                       float* __restrict__ out) {
  __shared__ float sc[LL];
  __shared__ float qs[DD];
  __shared__ float red[256];
  int blk = blockIdx.x;  // (b*H+h)*40 + j
  int j = blk % UU;
  int bh = blk / UU;
  int b = bh >> 3;
  int h = bh & 7;
  int l = mtop[bh * UU + j];
  int t = threadIdx.x;
  if (t < DD) qs[t] = q[(((size_t)b * LL + l) * HH + h) * DD + t];
  __syncthreads();
  int lane = t & 63;
  int wv = t >> 6;  // 0..3
  float qv = qs[lane];
  // scores = scale * q . k_row
  for (int row = wv; row < LL; row += 4) {
    float val = qv * k[(((size_t)b * LL + row) * HH + h) * DD + lane];
#pragma unroll
    for (int off = 32; off; off >>= 1) val += __shfl_xor(val, off);
    if (lane == 0) sc[row] = val * 0.125f;  // 1/sqrt(64)
  }
  __syncthreads();
  // block max
  float mx = -1.0e30f;
  for (int i = t; i < LL; i += 256) mx = fmaxf(mx, sc[i]);
  red[t] = mx;
  __syncthreads();
  for (int off = 128; off; off >>= 1) {
    if (t < off) red[t] = fmaxf(red[t], red[t + off]);
    __syncthreads();
  }
  mx = red[0];
  __syncthreads();
  // exp + sum
  float psum = 0.0f;
  for (int i = t; i < LL; i += 256) {
    float e = expf(sc[i] - mx);
    sc[i] = e;
    psum += e;
  }
  red[t] = psum;
  __syncthreads();
  for (int off = 128; off; off >>= 1) {
    if (t < off) red[t] += red[t + off];
    __syncthreads();
  }
  float inv = 1.0f / red[0];
  __syncthreads();
  // PV: thread t handles d=lane, key rows wv::4
  float acc = 0.0f;
  for (int row = wv; row < LL; row += 4) {
    acc += sc[row] * v[(((size_t)b * LL + row) * HH + h) * DD + lane];
  }
  red[t] = acc;
  __syncthreads();
  if (t < DD) {
    float r = red[t] + red[t + 64] + red[t + 128] + red[t + 192];
    out[(((size_t)b * LL + l) * HH + h) * DD + t] = r * inv;
  }
}

extern "C" void kernel_launch(void* const* d_in, const int* in_sizes, int n_in,
                              void* d_out, int out_size, void* d_ws, size_t ws_size,
                              hipStream_t stream) {
  const float* q = (const float*)d_in[0];
  const float* k = (const float*)d_in[1];
  const float* v = (const float*)d_in[2];
  float* out = (float*)d_out;

  char* ws = (char*)d_ws;
  double* M = (double*)(ws);                       // 65536 * 8 = 524288
  int* idx = (int*)(ws + 524288);                  // 81920 * 4 = 327680 -> 851968
  int* mtop = (int*)(ws + 851968);                 // 1280 * 4 = 5120   -> 857088
  float* vmean = (float*)(ws + 857088);            // 2048 * 4 = 8192   -> 865280

  k_build_idx<<<(NIDX + 255) / 256, 256, 0, stream>>>(idx);
  k_scores_M<<<BHL / 4, 256, 0, stream>>>(q, k, idx, M);
  k_topk<<<BB * HH, 256, 0, stream>>>(M, mtop);
  k_vmean<<<(BB * HH * DD + 255) / 256, 256, 0, stream>>>(v, vmean);
  k_fill<<<(BB * LL * HH * DD) / 256, 256, 0, stream>>>(vmean, out);
  k_attn<<<BB * HH * UU, 256, 0, stream>>>(q, k, v, mtop, out);
}

// Round 3
// 400.357 us; speedup vs baseline: 2.2075x; 2.2075x over previous
//
#include <hip/hip_runtime.h>
#include <hip/hip_bf16.h>
#include <math.h>
#include <stdint.h>

// (B, L, H, D) = (4, 2048, 8, 64); FACTOR=5 => U_part = u = 40.
static constexpr int BB = 4;
static constexpr int LL = 2048;
static constexpr int HH = 8;
static constexpr int DD = 64;
static constexpr int UU = 40;
static constexpr int NSAMP = 40;
static constexpr int BHL = BB * HH * LL;   // 65536
static constexpr int NIDX = LL * NSAMP;    // 81920
static constexpr int ROWSTRIDE = HH * DD;  // 512 floats between consecutive l

// ---------------- Threefry-2x32 (JAX partitionable mode) ----------------
__device__ __forceinline__ uint32_t rotl32(uint32_t x, uint32_t n) {
  return (x << n) | (x >> (32u - n));
}

__device__ __forceinline__ void tf2x32(uint32_t k0, uint32_t k1,
                                       uint32_t x0, uint32_t x1,
                                       uint32_t& o0, uint32_t& o1) {
  uint32_t ks[3] = {k0, k1, k0 ^ k1 ^ 0x1BD11BDAu};
  x0 += ks[0];
  x1 += ks[1];
  const uint32_t rotA[4] = {13u, 15u, 26u, 6u};
  const uint32_t rotB[4] = {17u, 29u, 16u, 24u};
#pragma unroll
  for (int i = 0; i < 5; ++i) {
    const uint32_t* r = (i & 1) ? rotB : rotA;
#pragma unroll
    for (int j = 0; j < 4; ++j) {
      x0 += x1;
      x1 = rotl32(x1, r[j]);
      x1 ^= x0;
    }
    x0 += ks[(i + 1) % 3];
    x1 += ks[(i + 2) % 3] + (uint32_t)(i + 1);
  }
  o0 = x0;
  o1 = x1;
}

__global__ void k_build_idx(int* __restrict__ idx) {
  int i = blockIdx.x * 256 + threadIdx.x;
  if (i >= NIDX) return;
  uint32_t ka, kb;
  tf2x32(0u, 42u, 0u, 1u, ka, kb);  // split(key(42)) -> second subkey
  uint32_t o0, o1;
  tf2x32(ka, kb, 0u, (uint32_t)i, o0, o1);
  idx[i] = (int)((o0 ^ o1) & 2047u);  // partitionable random_bits: o0^o1
}

// M[b,h,q] = max_s - mean_s of sampled dots. One wave per (b,h,q).
// Lane layout: dc = lane&15 (d-chunk of 4 floats), r2 = lane>>4 (sample in group of 4).
__global__ void k_scores_M(const float* __restrict__ q, const float* __restrict__ k,
                           const int* __restrict__ idx, float* __restrict__ M) {
  int w = (blockIdx.x * blockDim.x + threadIdx.x) >> 6;
  int lane = threadIdx.x & 63;
  if (w >= BHL) return;
  int qq = w & (LL - 1);
  int h = (w >> 11) & (HH - 1);
  int b = w >> 14;
  int dc = lane & 15;
  int r2 = lane >> 4;
  const float4* qrow = (const float4*)(q + (((size_t)b * LL + qq) * HH + h) * DD);
  float4 qv = qrow[dc];
  const float* kbase = k + ((size_t)b * LL * HH + h) * DD;
  const int* ridx = idx + qq * NSAMP;
  float mx = -1.0e30f;
  float sm = 0.0f;
#pragma unroll
  for (int s = 0; s < NSAMP; s += 4) {
    int krow = ridx[s + r2];
    const float4* kr = (const float4*)(kbase + (size_t)krow * ROWSTRIDE);
    float4 kv = kr[dc];
    float p = qv.x * kv.x + qv.y * kv.y + qv.z * kv.z + qv.w * kv.w;
    p += __shfl_xor(p, 1);
    p += __shfl_xor(p, 2);
    p += __shfl_xor(p, 4);
    p += __shfl_xor(p, 8);
    float s0 = __shfl(p, 0), s1 = __shfl(p, 16), s2 = __shfl(p, 32), s3 = __shfl(p, 48);
    mx = fmaxf(fmaxf(mx, fmaxf(s0, s1)), fmaxf(s2, s3));
    sm += (s0 + s1) + (s2 + s3);
  }
  if (lane == 0) M[w] = mx - sm * (1.0f / (float)NSAMP);
}

// Top-40 per (b,h), lax.top_k tie-break (lower index wins).
__global__ void k_topk(const float* __restrict__ M, int* __restrict__ mtop) {
  __shared__ float sv[LL];
  __shared__ float rv[4];
  __shared__ int ri[4];
  int bh = blockIdx.x;
  int t = threadIdx.x;
  int wv = t >> 6, lane = t & 63;
  const float* m = M + (size_t)bh * LL;
  for (int i = t; i < LL; i += 256) sv[i] = m[i];
  __syncthreads();
  for (int it = 0; it < UU; ++it) {
    float best = -1.0e30f;
    int bi = 1 << 30;
    for (int i = t; i < LL; i += 256) {
      float vv = sv[i];
      if (vv > best) { best = vv; bi = i; }
    }
#pragma unroll
    for (int off = 32; off; off >>= 1) {
      float ov = __shfl_xor(best, off);
      int oi = __shfl_xor(bi, off);
      if (ov > best || (ov == best && oi < bi)) { best = ov; bi = oi; }
    }
    if (lane == 0) { rv[wv] = best; ri[wv] = bi; }
    __syncthreads();
    float wb = rv[0];
    int wi = ri[0];
#pragma unroll
    for (int jj = 1; jj < 4; ++jj) {
      if (rv[jj] > wb || (rv[jj] == wb && ri[jj] < wi)) { wb = rv[jj]; wi = ri[jj]; }
    }
    if (t == 0) {
      mtop[bh * UU + it] = wi;
      sv[wi] = -1.0e30f;
    }
    __syncthreads();
  }
}

// V_mean[b,h,d]; one block per (b,h).
__global__ void k_vmean(const float* __restrict__ v, float* __restrict__ vmean) {
  __shared__ float part[4][DD];
  int bh = blockIdx.x;
  int b = bh >> 3, h = bh & 7;
  int t = threadIdx.x;
  int wv = t >> 6, lane = t & 63;
  const float* base = v + ((size_t)b * LL * HH + h) * DD + lane;
  float s = 0.0f;
  for (int l = wv; l < LL; l += 4) s += base[(size_t)l * ROWSTRIDE];
  part[wv][lane] = s;
  __syncthreads();
  if (t < DD) {
    vmean[bh * DD + t] =
        ((part[0][t] + part[1][t]) + (part[2][t] + part[3][t])) * (1.0f / (float)LL);
  }
}

// out[b,l,h,:] = vmean[b,h,:]  (float4)
__global__ void k_fill(const float* __restrict__ vmean, float* __restrict__ out) {
  int f = blockIdx.x * 256 + threadIdx.x;  // over 1,048,576 float4s
  int d4 = f & 15;
  int h = (f >> 4) & 7;
  int b = f >> 18;
  ((float4*)out)[f] = ((const float4*)vmean)[(((b << 3) + h) << 4) + d4];
}

// Full attention for selected queries; block per (b,h,j).
__global__ void k_attn(const float* __restrict__ q, const float* __restrict__ k,
                       const float* __restrict__ v, const int* __restrict__ mtop,
                       float* __restrict__ out) {
  __shared__ float sc[LL];       // scores -> probs
  __shared__ float redm[4];
  __shared__ float reds[4];
  __shared__ float redp[4][DD];
  int blk = blockIdx.x;
  int j = blk % UU;
  int bh = blk / UU;
  int b = bh >> 3, h = bh & 7;
  int l = mtop[bh * UU + j];
  int t = threadIdx.x;
  int wv = t >> 6, lane = t & 63;
  int dc = t & 15, r2 = (t >> 4) & 3;

  const float4* qrow = (const float4*)(q + (((size_t)b * LL + l) * HH + h) * DD);
  float4 qv = qrow[dc];
  const float* kbase = k + ((size_t)b * LL * HH + h) * DD;

  // ---- QK^T: wave handles 4 rows per iter; lane=(r2,dc) ----
#pragma unroll 4
  for (int base = wv * 4; base < LL; base += 16) {
    int row = base + r2;
    const float4* krow = (const float4*)(kbase + (size_t)row * ROWSTRIDE);
    float4 kv = krow[dc];
    float p = qv.x * kv.x + qv.y * kv.y + qv.z * kv.z + qv.w * kv.w;
    p += __shfl_xor(p, 1);
    p += __shfl_xor(p, 2);
    p += __shfl_xor(p, 4);
    p += __shfl_xor(p, 8);
    if (dc == 0) sc[row] = p * 0.125f;  // 1/sqrt(64)
  }
  __syncthreads();

  // ---- max (wave shuffle + 4-entry combine) ----
  const float4* sc4 = (const float4*)sc;
  float4 ea0 = sc4[t];
  float4 ea1 = sc4[t + 256];
  float mx = fmaxf(fmaxf(fmaxf(ea0.x, ea0.y), fmaxf(ea0.z, ea0.w)),
                   fmaxf(fmaxf(ea1.x, ea1.y), fmaxf(ea1.z, ea1.w)));
#pragma unroll
  for (int off = 32; off; off >>= 1) mx = fmaxf(mx, __shfl_xor(mx, off));
  if (lane == 0) redm[wv] = mx;
  __syncthreads();
  mx = fmaxf(fmaxf(redm[0], redm[1]), fmaxf(redm[2], redm[3]));

  // ---- exp + sum ----
  ea0.x = expf(ea0.x - mx); ea0.y = expf(ea0.y - mx);
  ea0.z = expf(ea0.z - mx); ea0.w = expf(ea0.w - mx);
  ea1.x = expf(ea1.x - mx); ea1.y = expf(ea1.y - mx);
  ea1.z = expf(ea1.z - mx); ea1.w = expf(ea1.w - mx);
  float ps = ((ea0.x + ea0.y) + (ea0.z + ea0.w)) + ((ea1.x + ea1.y) + (ea1.z + ea1.w));
  float4* sc4w = (float4*)sc;
  sc4w[t] = ea0;
  sc4w[t + 256] = ea1;
#pragma unroll
  for (int off = 32; off; off >>= 1) ps += __shfl_xor(ps, off);
  if (lane == 0) reds[wv] = ps;
  __syncthreads();
  float inv = 1.0f / ((reds[0] + reds[1]) + (reds[2] + reds[3]));

  // ---- PV: lane = d; wave handles l-groups of 4 ----
  const float* vbase = v + ((size_t)b * LL * HH + h) * DD + lane;
  float acc = 0.0f;
#pragma unroll 2
  for (int base = wv * 4; base < LL; base += 16) {
    float4 p4 = sc4[base >> 2];
    acc += p4.x * vbase[(size_t)(base + 0) * ROWSTRIDE];
    acc += p4.y * vbase[(size_t)(base + 1) * ROWSTRIDE];
    acc += p4.z * vbase[(size_t)(base + 2) * ROWSTRIDE];
    acc += p4.w * vbase[(size_t)(base + 3) * ROWSTRIDE];
  }
  redp[wv][lane] = acc;
  __syncthreads();
  if (t < DD) {
    float r = (redp[0][t] + redp[1][t]) + (redp[2][t] + redp[3][t]);
    out[(((size_t)b * LL + l) * HH + h) * DD + t] = r * inv;
  }
}

extern "C" void kernel_launch(void* const* d_in, const int* in_sizes, int n_in,
                              void* d_out, int out_size, void* d_ws, size_t ws_size,
                              hipStream_t stream) {
  const float* q = (const float*)d_in[0];
  const float* k = (const float*)d_in[1];
  const float* v = (const float*)d_in[2];
  float* out = (float*)d_out;

  char* ws = (char*)d_ws;
  float* M = (float*)(ws);                 // 65536*4 = 262144
  int* idx = (int*)(ws + 262144);          // 81920*4 = 327680 -> 589824
  int* mtop = (int*)(ws + 589824);         // 1280*4  = 5120   -> 594944
  float* vmean = (float*)(ws + 594944);    // 2048*4  = 8192   -> 603136

  k_build_idx<<<(NIDX + 255) / 256, 256, 0, stream>>>(idx);
  k_scores_M<<<BHL / 4, 256, 0, stream>>>(q, k, idx, M);
  k_topk<<<BB * HH, 256, 0, stream>>>(M, mtop);
  k_vmean<<<BB * HH, 256, 0, stream>>>(v, vmean);
  k_fill<<<(BB * LL * HH * DD / 4) / 256, 256, 0, stream>>>(vmean, out);
  k_attn<<<BB * HH * UU, 256, 0, stream>>>(q, k, v, mtop, out);
}

// Round 4
// 283.841 us; speedup vs baseline: 3.1137x; 1.4105x over previous
//
#include <hip/hip_runtime.h>
#include <hip/hip_bf16.h>
#include <math.h>
#include <stdint.h>

// (B, L, H, D) = (4, 2048, 8, 64); FACTOR=5 => U_part = u = 40.
static constexpr int BB = 4;
static constexpr int LL = 2048;
static constexpr int HH = 8;
static constexpr int DD = 64;
static constexpr int UU = 40;
static constexpr int NSAMP = 40;
static constexpr int BHL = BB * HH * LL;   // 65536
static constexpr int NIDX = LL * NSAMP;    // 81920
static constexpr int ROWSTRIDE = HH * DD;  // 512 floats between consecutive l
static constexpr int VCHUNKS = 64;         // L-chunks per (b,h) for vmean phase 1

// ---------------- Threefry-2x32 (JAX partitionable mode) ----------------
__device__ __forceinline__ uint32_t rotl32(uint32_t x, uint32_t n) {
  return (x << n) | (x >> (32u - n));
}

__device__ __forceinline__ void tf2x32(uint32_t k0, uint32_t k1,
                                       uint32_t x0, uint32_t x1,
                                       uint32_t& o0, uint32_t& o1) {
  uint32_t ks[3] = {k0, k1, k0 ^ k1 ^ 0x1BD11BDAu};
  x0 += ks[0];
  x1 += ks[1];
  const uint32_t rotA[4] = {13u, 15u, 26u, 6u};
  const uint32_t rotB[4] = {17u, 29u, 16u, 24u};
#pragma unroll
  for (int i = 0; i < 5; ++i) {
    const uint32_t* r = (i & 1) ? rotB : rotA;
#pragma unroll
    for (int j = 0; j < 4; ++j) {
      x0 += x1;
      x1 = rotl32(x1, r[j]);
      x1 ^= x0;
    }
    x0 += ks[(i + 1) % 3];
    x1 += ks[(i + 2) % 3] + (uint32_t)(i + 1);
  }
  o0 = x0;
  o1 = x1;
}

__global__ void k_build_idx(int* __restrict__ idx) {
  int i = blockIdx.x * 256 + threadIdx.x;
  if (i >= NIDX) return;
  uint32_t ka, kb;
  tf2x32(0u, 42u, 0u, 1u, ka, kb);  // split(key(42)) -> second subkey
  uint32_t o0, o1;
  tf2x32(ka, kb, 0u, (uint32_t)i, o0, o1);
  idx[i] = (int)((o0 ^ o1) & 2047u);  // partitionable random_bits: o0^o1
}

// M[b,h,q] = max_s - mean_s of sampled dots. One wave per (b,h,q).
__global__ void k_scores_M(const float* __restrict__ q, const float* __restrict__ k,
                           const int* __restrict__ idx, float* __restrict__ M) {
  int w = (blockIdx.x * blockDim.x + threadIdx.x) >> 6;
  int lane = threadIdx.x & 63;
  if (w >= BHL) return;
  int qq = w & (LL - 1);
  int h = (w >> 11) & (HH - 1);
  int b = w >> 14;
  int dc = lane & 15;
  int r2 = lane >> 4;
  const float4* qrow = (const float4*)(q + (((size_t)b * LL + qq) * HH + h) * DD);
  float4 qv = qrow[dc];
  const float* kbase = k + ((size_t)b * LL * HH + h) * DD;
  const int* ridx = idx + qq * NSAMP;
  float mx = -1.0e30f;
  float sm = 0.0f;
#pragma unroll
  for (int s = 0; s < NSAMP; s += 4) {
    int krow = ridx[s + r2];
    const float4* kr = (const float4*)(kbase + (size_t)krow * ROWSTRIDE);
    float4 kv = kr[dc];
    float p = qv.x * kv.x + qv.y * kv.y + qv.z * kv.z + qv.w * kv.w;
    p += __shfl_xor(p, 1);
    p += __shfl_xor(p, 2);
    p += __shfl_xor(p, 4);
    p += __shfl_xor(p, 8);
    float s0 = __shfl(p, 0), s1 = __shfl(p, 16), s2 = __shfl(p, 32), s3 = __shfl(p, 48);
    mx = fmaxf(fmaxf(mx, fmaxf(s0, s1)), fmaxf(s2, s3));
    sm += (s0 + s1) + (s2 + s3);
  }
  if (lane == 0) M[w] = mx - sm * (1.0f / (float)NSAMP);
}

// Top-40 per (b,h), lax.top_k tie-break (lower index wins).
__global__ void k_topk(const float* __restrict__ M, int* __restrict__ mtop) {
  __shared__ float sv[LL];
  __shared__ float rv[4];
  __shared__ int ri[4];
  int bh = blockIdx.x;
  int t = threadIdx.x;
  int wv = t >> 6, lane = t & 63;
  const float* m = M + (size_t)bh * LL;
  for (int i = t; i < LL; i += 256) sv[i] = m[i];
  __syncthreads();
  for (int it = 0; it < UU; ++it) {
    float best = -1.0e30f;
    int bi = 1 << 30;
    for (int i = t; i < LL; i += 256) {
      float vv = sv[i];
      if (vv > best) { best = vv; bi = i; }
    }
#pragma unroll
    for (int off = 32; off; off >>= 1) {
      float ov = __shfl_xor(best, off);
      int oi = __shfl_xor(bi, off);
      if (ov > best || (ov == best && oi < bi)) { best = ov; bi = oi; }
    }
    if (lane == 0) { rv[wv] = best; ri[wv] = bi; }
    __syncthreads();
    float wb = rv[0];
    int wi = ri[0];
#pragma unroll
    for (int jj = 1; jj < 4; ++jj) {
      if (rv[jj] > wb || (rv[jj] == wb && ri[jj] < wi)) { wb = rv[jj]; wi = ri[jj]; }
    }
    if (t == 0) {
      mtop[bh * UU + it] = wi;
      sv[wi] = -1.0e30f;
    }
    __syncthreads();
  }
}

// V_mean phase 1: grid = 32 bh * 64 chunks; each block sums 32 rows -> partial[bid][64].
__global__ void k_vmean_part(const float* __restrict__ v, float* __restrict__ partial) {
  __shared__ float part[4][DD];
  int bid = blockIdx.x;
  int bh = bid >> 6;          // /VCHUNKS
  int chunk = bid & 63;
  int b = bh >> 3, h = bh & 7;
  int t = threadIdx.x;
  int wv = t >> 6, lane = t & 63;
  int l0 = chunk * (LL / VCHUNKS);  // 32 rows
  const float* base = v + ((size_t)b * LL * HH + h) * DD + lane;
  float s = 0.0f;
#pragma unroll
  for (int r = wv; r < LL / VCHUNKS; r += 4) s += base[(size_t)(l0 + r) * ROWSTRIDE];
  part[wv][lane] = s;
  __syncthreads();
  if (t < DD) {
    partial[(size_t)bid * DD + t] =
        (part[0][t] + part[1][t]) + (part[2][t] + part[3][t]);
  }
}

// V_mean phase 2: 32 blocks x 64 threads; vmean[bh][d] = sum_c partial[bh*64+c][d] / LL.
__global__ void k_vmean_final(const float* __restrict__ partial, float* __restrict__ vmean) {
  int bh = blockIdx.x;
  int d = threadIdx.x;
  const float* p = partial + (size_t)bh * VCHUNKS * DD + d;
  float s = 0.0f;
#pragma unroll
  for (int c = 0; c < VCHUNKS; ++c) s += p[(size_t)c * DD];
  vmean[bh * DD + d] = s * (1.0f / (float)LL);
}

// out[b,l,h,:] = vmean[b,h,:]  (float4)
__global__ void k_fill(const float* __restrict__ vmean, float* __restrict__ out) {
  int f = blockIdx.x * 256 + threadIdx.x;  // over 1,048,576 float4s
  int d4 = f & 15;
  int h = (f >> 4) & 7;
  int b = f >> 18;
  ((float4*)out)[f] = ((const float4*)vmean)[(((b << 3) + h) << 4) + d4];
}

// Full attention for selected queries; block per (b,h,j).
__global__ void k_attn(const float* __restrict__ q, const float* __restrict__ k,
                       const float* __restrict__ v, const int* __restrict__ mtop,
                       float* __restrict__ out) {
  __shared__ float sc[LL];       // scores -> probs
  __shared__ float redm[4];
  __shared__ float reds[4];
  __shared__ float redp[4][DD];
  int blk = blockIdx.x;
  int j = blk % UU;
  int bh = blk / UU;
  int b = bh >> 3, h = bh & 7;
  int l = mtop[bh * UU + j];
  int t = threadIdx.x;
  int wv = t >> 6, lane = t & 63;
  int dc = t & 15, r2 = (t >> 4) & 3;

  const float4* qrow = (const float4*)(q + (((size_t)b * LL + l) * HH + h) * DD);
  float4 qv = qrow[dc];
  const float* kbase = k + ((size_t)b * LL * HH + h) * DD;

  // ---- QK^T: wave handles 4 rows per iter; lane=(r2,dc) ----
#pragma unroll 4
  for (int base = wv * 4; base < LL; base += 16) {
    int row = base + r2;
    const float4* krow = (const float4*)(kbase + (size_t)row * ROWSTRIDE);
    float4 kv = krow[dc];
    float p = qv.x * kv.x + qv.y * kv.y + qv.z * kv.z + qv.w * kv.w;
    p += __shfl_xor(p, 1);
    p += __shfl_xor(p, 2);
    p += __shfl_xor(p, 4);
    p += __shfl_xor(p, 8);
    if (dc == 0) sc[row] = p * 0.125f;  // 1/sqrt(64)
  }
  __syncthreads();

  // ---- max (wave shuffle + 4-entry combine) ----
  const float4* sc4 = (const float4*)sc;
  float4 ea0 = sc4[t];
  float4 ea1 = sc4[t + 256];
  float mx = fmaxf(fmaxf(fmaxf(ea0.x, ea0.y), fmaxf(ea0.z, ea0.w)),
                   fmaxf(fmaxf(ea1.x, ea1.y), fmaxf(ea1.z, ea1.w)));
#pragma unroll
  for (int off = 32; off; off >>= 1) mx = fmaxf(mx, __shfl_xor(mx, off));
  if (lane == 0) redm[wv] = mx;
  __syncthreads();
  mx = fmaxf(fmaxf(redm[0], redm[1]), fmaxf(redm[2], redm[3]));

  // ---- exp + sum ----
  ea0.x = expf(ea0.x - mx); ea0.y = expf(ea0.y - mx);
  ea0.z = expf(ea0.z - mx); ea0.w = expf(ea0.w - mx);
  ea1.x = expf(ea1.x - mx); ea1.y = expf(ea1.y - mx);
  ea1.z = expf(ea1.z - mx); ea1.w = expf(ea1.w - mx);
  float ps = ((ea0.x + ea0.y) + (ea0.z + ea0.w)) + ((ea1.x + ea1.y) + (ea1.z + ea1.w));
  float4* sc4w = (float4*)sc;
  sc4w[t] = ea0;
  sc4w[t + 256] = ea1;
#pragma unroll
  for (int off = 32; off; off >>= 1) ps += __shfl_xor(ps, off);
  if (lane == 0) reds[wv] = ps;
  __syncthreads();
  float inv = 1.0f / ((reds[0] + reds[1]) + (reds[2] + reds[3]));

  // ---- PV: lane = d; wave handles l-groups of 4 ----
  const float* vbase = v + ((size_t)b * LL * HH + h) * DD + lane;
  float acc = 0.0f;
#pragma unroll 2
  for (int base = wv * 4; base < LL; base += 16) {
    float4 p4 = sc4[base >> 2];
    acc += p4.x * vbase[(size_t)(base + 0) * ROWSTRIDE];
    acc += p4.y * vbase[(size_t)(base + 1) * ROWSTRIDE];
    acc += p4.z * vbase[(size_t)(base + 2) * ROWSTRIDE];
    acc += p4.w * vbase[(size_t)(base + 3) * ROWSTRIDE];
  }
  redp[wv][lane] = acc;
  __syncthreads();
  if (t < DD) {
    float r = (redp[0][t] + redp[1][t]) + (redp[2][t] + redp[3][t]);
    out[(((size_t)b * LL + l) * HH + h) * DD + t] = r * inv;
  }
}

extern "C" void kernel_launch(void* const* d_in, const int* in_sizes, int n_in,
                              void* d_out, int out_size, void* d_ws, size_t ws_size,
                              hipStream_t stream) {
  const float* q = (const float*)d_in[0];
  const float* k = (const float*)d_in[1];
  const float* v = (const float*)d_in[2];
  float* out = (float*)d_out;

  char* ws = (char*)d_ws;
  float* M = (float*)(ws);                 // 65536*4 = 262144
  int* idx = (int*)(ws + 262144);          // 81920*4 = 327680 -> 589824
  int* mtop = (int*)(ws + 589824);         // 1280*4  = 5120   -> 594944
  float* vmean = (float*)(ws + 594944);    // 2048*4  = 8192   -> 603136
  // partial aliases M+idx (both dead after k_topk): 2048*64*4 = 524288 bytes
  float* partial = (float*)(ws);

  k_build_idx<<<(NIDX + 255) / 256, 256, 0, stream>>>(idx);
  k_scores_M<<<BHL / 4, 256, 0, stream>>>(q, k, idx, M);
  k_topk<<<BB * HH, 256, 0, stream>>>(M, mtop);
  k_vmean_part<<<BB * HH * VCHUNKS, 256, 0, stream>>>(v, partial);
  k_vmean_final<<<BB * HH, DD, 0, stream>>>(partial, vmean);
  k_fill<<<(BB * LL * HH * DD / 4) / 256, 256, 0, stream>>>(vmean, out);
  k_attn<<<BB * HH * UU, 256, 0, stream>>>(q, k, v, mtop, out);
}

// Round 6
// 212.768 us; speedup vs baseline: 4.1537x; 1.3340x over previous
//
#include <hip/hip_runtime.h>
#include <hip/hip_bf16.h>
#include <math.h>
#include <stdint.h>

// (B, L, H, D) = (4, 2048, 8, 64); FACTOR=5 => U_part = u = 40.
static constexpr int BB = 4;
static constexpr int LL = 2048;
static constexpr int HH = 8;
static constexpr int DD = 64;
static constexpr int UU = 40;
static constexpr int NSAMP = 40;
static constexpr int BHL = BB * HH * LL;   // 65536
static constexpr int NIDX = LL * NSAMP;    // 81920
static constexpr int ROWSTRIDE = HH * DD;  // 512 floats between consecutive l
static constexpr int VCHUNKS = 64;
static constexpr int NC = 16;              // KV chunks per (b,h) for split attn
static constexpr int CROWS = LL / NC;      // 128
static constexpr int NBLK = BB * HH * NC;  // 512

// ---- workspace layout (big path) ----
// pm [NBLK*UU] f32 @ 0            (81920)
// ps [NBLK*UU] f32 @ 81920        (81920)
// pacc [NBLK*UU*DD] f32 @ 163840  (5242880)  -> 5406720
//   early-lifetime aliases inside [0, 5406720): M@0 (262144), idx@262144 (327680),
//   vmean_partial@0 (524288) - all dead before k_attn_part runs.
// mtop @ 5406720 (5120), vmean @ 5411840 (8192) -> WS_NEED 5420032
static constexpr size_t WS_NEED = 5420032;

// ---------------- Threefry-2x32 (JAX partitionable mode) ----------------
__device__ __forceinline__ uint32_t rotl32(uint32_t x, uint32_t n) {
  return (x << n) | (x >> (32u - n));
}

__device__ __forceinline__ void tf2x32(uint32_t k0, uint32_t k1,
                                       uint32_t x0, uint32_t x1,
                                       uint32_t& o0, uint32_t& o1) {
  uint32_t ks[3] = {k0, k1, k0 ^ k1 ^ 0x1BD11BDAu};
  x0 += ks[0];
  x1 += ks[1];
  const uint32_t rotA[4] = {13u, 15u, 26u, 6u};
  const uint32_t rotB[4] = {17u, 29u, 16u, 24u};
#pragma unroll
  for (int i = 0; i < 5; ++i) {
    const uint32_t* r = (i & 1) ? rotB : rotA;
#pragma unroll
    for (int j = 0; j < 4; ++j) {
      x0 += x1;
      x1 = rotl32(x1, r[j]);
      x1 ^= x0;
    }
    x0 += ks[(i + 1) % 3];
    x1 += ks[(i + 2) % 3] + (uint32_t)(i + 1);
  }
  o0 = x0;
  o1 = x1;
}

__global__ void k_build_idx(int* __restrict__ idx) {
  int i = blockIdx.x * 256 + threadIdx.x;
  if (i >= NIDX) return;
  uint32_t ka, kb;
  tf2x32(0u, 42u, 0u, 1u, ka, kb);  // split(key(42)) -> second subkey
  uint32_t o0, o1;
  tf2x32(ka, kb, 0u, (uint32_t)i, o0, o1);
  idx[i] = (int)((o0 ^ o1) & 2047u);  // partitionable random_bits: o0^o1
}

__device__ __forceinline__ float dot4(float4 a, float4 b) {
  return a.x * b.x + a.y * b.y + a.z * b.z + a.w * b.w;
}

// M[b,h,q] = max_s - mean_s over 40 sampled dots. One wave per (b,h,q).
// Lane = (rr in 0..7 sample slot, dc in 0..7 d-chunk of 8 floats).
__global__ void k_scores_M(const float* __restrict__ q, const float* __restrict__ k,
                           const int* __restrict__ idx, float* __restrict__ M) {
  int w = (blockIdx.x * blockDim.x + threadIdx.x) >> 6;
  int lane = threadIdx.x & 63;
  if (w >= BHL) return;
  int qq = w & (LL - 1);
  int h = (w >> 11) & (HH - 1);
  int b = w >> 14;
  int rr = lane >> 3;  // sample slot within group of 8
  int dc = lane & 7;   // 8-float chunk of d
  const float* qrow = q + (((size_t)b * LL + qq) * HH + h) * DD;
  float4 q0 = ((const float4*)qrow)[dc * 2];
  float4 q1 = ((const float4*)qrow)[dc * 2 + 1];
  const float* kbase = k + ((size_t)b * LL * HH + h) * DD;
  const int* ridx = idx + qq * NSAMP;
  int kr[5];
#pragma unroll
  for (int it = 0; it < 5; ++it) kr[it] = ridx[it * 8 + rr];
  float mx = -1.0e30f, sm = 0.0f;
#pragma unroll
  for (int it = 0; it < 5; ++it) {
    const float4* kp = (const float4*)(kbase + (size_t)kr[it] * ROWSTRIDE);
    float p = dot4(q0, kp[dc * 2]) + dot4(q1, kp[dc * 2 + 1]);
    p += __shfl_xor(p, 1);
    p += __shfl_xor(p, 2);
    p += __shfl_xor(p, 4);  // reduce over dc
    mx = fmaxf(mx, p);
    sm += p;
  }
#pragma unroll
  for (int off = 8; off <= 32; off <<= 1) {  // reduce over rr
    mx = fmaxf(mx, __shfl_xor(mx, off));
    sm += __shfl_xor(sm, off);
  }
  if (lane == 0) M[w] = mx - sm * (1.0f / (float)NSAMP);
}

// Top-40 per (b,h), lax.top_k tie-break (lower index wins).
__global__ void k_topk(const float* __restrict__ M, int* __restrict__ mtop) {
  __shared__ float sv[LL];
  __shared__ float rv[4];
  __shared__ int ri[4];
  int bh = blockIdx.x;
  int t = threadIdx.x;
  int wv = t >> 6, lane = t & 63;
  const float* m = M + (size_t)bh * LL;
  for (int i = t; i < LL; i += 256) sv[i] = m[i];
  __syncthreads();
  for (int it = 0; it < UU; ++it) {
    float best = -1.0e30f;
    int bi = 1 << 30;
    for (int i = t; i < LL; i += 256) {
      float vv = sv[i];
      if (vv > best) { best = vv; bi = i; }
    }
#pragma unroll
    for (int off = 32; off; off >>= 1) {
      float ov = __shfl_xor(best, off);
      int oi = __shfl_xor(bi, off);
      if (ov > best || (ov == best && oi < bi)) { best = ov; bi = oi; }
    }
    if (lane == 0) { rv[wv] = best; ri[wv] = bi; }
    __syncthreads();
    float wb = rv[0];
    int wi = ri[0];
#pragma unroll
    for (int jj = 1; jj < 4; ++jj) {
      if (rv[jj] > wb || (rv[jj] == wb && ri[jj] < wi)) { wb = rv[jj]; wi = ri[jj]; }
    }
    if (t == 0) {
      mtop[bh * UU + it] = wi;
      sv[wi] = -1.0e30f;
    }
    __syncthreads();
  }
}

// V_mean phase 1: 2048 blocks; each sums 32 rows of one (b,h).
__global__ void k_vmean_part(const float* __restrict__ v, float* __restrict__ partial) {
  __shared__ float part[4][DD];
  int bid = blockIdx.x;
  int bh = bid >> 6;
  int chunk = bid & 63;
  int b = bh >> 3, h = bh & 7;
  int t = threadIdx.x;
  int wv = t >> 6, lane = t & 63;
  int l0 = chunk * (LL / VCHUNKS);
  const float* base = v + ((size_t)b * LL * HH + h) * DD + lane;
  float s = 0.0f;
#pragma unroll
  for (int r = wv; r < LL / VCHUNKS; r += 4) s += base[(size_t)(l0 + r) * ROWSTRIDE];
  part[wv][lane] = s;
  __syncthreads();
  if (t < DD) {
    partial[(size_t)bid * DD + t] =
        (part[0][t] + part[1][t]) + (part[2][t] + part[3][t]);
  }
}

__global__ void k_vmean_final(const float* __restrict__ partial, float* __restrict__ vmean) {
  int bh = blockIdx.x;
  int d = threadIdx.x;
  const float* p = partial + (size_t)bh * VCHUNKS * DD + d;
  float s = 0.0f;
#pragma unroll
  for (int c = 0; c < VCHUNKS; ++c) s += p[(size_t)c * DD];
  vmean[bh * DD + d] = s * (1.0f / (float)LL);
}

__global__ void k_fill(const float* __restrict__ vmean, float* __restrict__ out) {
  int f = blockIdx.x * 256 + threadIdx.x;
  int d4 = f & 15;
  int h = (f >> 4) & 7;
  int b = f >> 18;
  ((float4*)out)[f] = ((const float4*)vmean)[(((b << 3) + h) << 4) + d4];
}

// ---- split-KV attention, phase 1: block = (bh, chunk of 128 K rows) ----
__global__ void __launch_bounds__(256)
k_attn_part(const float* __restrict__ q, const float* __restrict__ k,
            const float* __restrict__ v, const int* __restrict__ mtop,
            float* __restrict__ pm, float* __restrict__ ps,
            float* __restrict__ pacc) {
  __shared__ float qs[UU][DD];      // 10 KB
  __shared__ float sc[UU][CROWS];   // 20 KB
  int blk = blockIdx.x;             // bh*NC + c
  int c = blk & (NC - 1);
  int bh = blk >> 4;
  int b = bh >> 3, h = bh & 7;
  int t = threadIdx.x;
  int wv = t >> 6, lane = t & 63;
  int l0 = c * CROWS;

  // stage gathered Q rows
  for (int i = t; i < UU * DD; i += 256) {
    int j = i >> 6, d = i & 63;
    int l = mtop[bh * UU + j];
    qs[j][d] = q[(((size_t)b * LL + l) * HH + h) * DD + d];
  }
  __syncthreads();

  const float* kbase = k + ((size_t)b * LL * HH + h) * DD;

  // ---- QK^T: wave holds its 32 K rows in registers (16 rows x 4 d-chunks) ----
  int rr = lane & 15, dcq = lane >> 4;  // dcq in 0..3, 16 floats each
  float4 kv0[4], kv1[4];
  {
    const float* kr0 = kbase + (size_t)(l0 + wv * 32 + rr) * ROWSTRIDE + dcq * 16;
    const float* kr1 = kbase + (size_t)(l0 + wv * 32 + 16 + rr) * ROWSTRIDE + dcq * 16;
#pragma unroll
    for (int i = 0; i < 4; ++i) {
      kv0[i] = *(const float4*)(kr0 + i * 4);
      kv1[i] = *(const float4*)(kr1 + i * 4);
    }
  }
#pragma unroll 4
  for (int j = 0; j < UU; ++j) {
    const float* qp = &qs[j][dcq * 16];
    float4 qa = *(const float4*)(qp);
    float4 qb = *(const float4*)(qp + 4);
    float4 qc = *(const float4*)(qp + 8);
    float4 qd = *(const float4*)(qp + 12);
    float p0 = dot4(qa, kv0[0]) + dot4(qb, kv0[1]) + dot4(qc, kv0[2]) + dot4(qd, kv0[3]);
    float p1 = dot4(qa, kv1[0]) + dot4(qb, kv1[1]) + dot4(qc, kv1[2]) + dot4(qd, kv1[3]);
    p0 += __shfl_xor(p0, 16);
    p0 += __shfl_xor(p0, 32);
    p1 += __shfl_xor(p1, 16);
    p1 += __shfl_xor(p1, 32);
    if (lane < 16) {
      sc[j][wv * 32 + lane] = p0 * 0.125f;
      sc[j][wv * 32 + 16 + lane] = p1 * 0.125f;
    }
  }
  __syncthreads();

  // ---- per-query chunk max + exp + sum (wave owns queries wv*10..wv*10+9) ----
#pragma unroll
  for (int jj = 0; jj < 10; ++jj) {
    int j = wv * 10 + jj;
    float a0 = sc[j][lane];
    float a1 = sc[j][lane + 64];
    float mx = fmaxf(a0, a1);
#pragma unroll
    for (int off = 32; off; off >>= 1) mx = fmaxf(mx, __shfl_xor(mx, off));
    float e0 = expf(a0 - mx), e1 = expf(a1 - mx);
    sc[j][lane] = e0;
    sc[j][lane + 64] = e1;
    float s = e0 + e1;
#pragma unroll
    for (int off = 32; off; off >>= 1) s += __shfl_xor(s, off);
    if (lane == 0) {
      pm[(size_t)blk * UU + j] = mx;
      ps[(size_t)blk * UU + j] = s;
    }
  }

  // ---- PV partial: lane = d; acc over this chunk's 128 rows for 10 queries ----
  const float* vbase = v + ((size_t)b * LL * HH + h) * DD + lane;
  float acc[10];
#pragma unroll
  for (int jj = 0; jj < 10; ++jj) acc[jj] = 0.0f;
  for (int r = 0; r < CROWS; r += 4) {
    float v0 = vbase[(size_t)(l0 + r + 0) * ROWSTRIDE];
    float v1 = vbase[(size_t)(l0 + r + 1) * ROWSTRIDE];
    float v2 = vbase[(size_t)(l0 + r + 2) * ROWSTRIDE];
    float v3 = vbase[(size_t)(l0 + r + 3) * ROWSTRIDE];
#pragma unroll
    for (int jj = 0; jj < 10; ++jj) {
      int j = wv * 10 + jj;
      float4 p4 = *(const float4*)&sc[j][r];  // wave-uniform broadcast
      acc[jj] += p4.x * v0 + p4.y * v1 + p4.z * v2 + p4.w * v3;
    }
  }
#pragma unroll
  for (int jj = 0; jj < 10; ++jj) {
    int j = wv * 10 + jj;
    pacc[((size_t)blk * UU + j) * DD + lane] = acc[jj];
  }
}

// ---- split-KV attention, phase 2: one wave per (bh, j) combines 16 chunks ----
__global__ void k_attn_comb(const float* __restrict__ pm, const float* __restrict__ ps,
                            const float* __restrict__ pacc, const int* __restrict__ mtop,
                            float* __restrict__ out) {
  int wid = (blockIdx.x * 256 + threadIdx.x) >> 6;
  int lane = threadIdx.x & 63;
  if (wid >= BB * HH * UU) return;
  int j = wid % UU;
  int bh = wid / UU;
  int b = bh >> 3, h = bh & 7;
  float mv = (lane < NC) ? pm[((size_t)(bh * NC + lane)) * UU + j] : -1.0e30f;
  float mx = mv;
#pragma unroll
  for (int off = 8; off; off >>= 1) mx = fmaxf(mx, __shfl_xor(mx, off));
  mx = __shfl(mx, 0);
  float e = (lane < NC) ? expf(mv - mx) : 0.0f;
  float sv = (lane < NC) ? ps[((size_t)(bh * NC + lane)) * UU + j] * e : 0.0f;
  float st = sv;
#pragma unroll
  for (int off = 8; off; off >>= 1) st += __shfl_xor(st, off);
  st = __shfl(st, 0);
  float a = 0.0f;
#pragma unroll
  for (int c = 0; c < NC; ++c) {
    float ec = __shfl(e, c);
    a += ec * pacc[((size_t)(bh * NC + c) * UU + j) * DD + lane];
  }
  int l = mtop[bh * UU + j];
  out[(((size_t)b * LL + l) * HH + h) * DD + lane] = a / st;
}

// ---- fallback mono attention (small-ws path), as in R4 ----
__global__ void k_attn_mono(const float* __restrict__ q, const float* __restrict__ k,
                            const float* __restrict__ v, const int* __restrict__ mtop,
                            float* __restrict__ out) {
  __shared__ float sc[LL];
  __shared__ float redm[4];
  __shared__ float reds[4];
  __shared__ float redp[4][DD];
  int blk = blockIdx.x;
  int j = blk % UU;
  int bh = blk / UU;
  int b = bh >> 3, h = bh & 7;
  int l = mtop[bh * UU + j];
  int t = threadIdx.x;
  int wv = t >> 6, lane = t & 63;
  int dc = t & 15, r2 = (t >> 4) & 3;
  const float4* qrow = (const float4*)(q + (((size_t)b * LL + l) * HH + h) * DD);
  float4 qv = qrow[dc];
  const float* kbase = k + ((size_t)b * LL * HH + h) * DD;
#pragma unroll 4
  for (int base = wv * 4; base < LL; base += 16) {
    int row = base + r2;
    const float4* krow = (const float4*)(kbase + (size_t)row * ROWSTRIDE);
    float4 kv = krow[dc];
    float p = dot4(qv, kv);
    p += __shfl_xor(p, 1);
    p += __shfl_xor(p, 2);
    p += __shfl_xor(p, 4);
    p += __shfl_xor(p, 8);
    if (dc == 0) sc[row] = p * 0.125f;
  }
  __syncthreads();
  const float4* sc4 = (const float4*)sc;
  float4 ea0 = sc4[t];
  float4 ea1 = sc4[t + 256];
  float mx = fmaxf(fmaxf(fmaxf(ea0.x, ea0.y), fmaxf(ea0.z, ea0.w)),
                   fmaxf(fmaxf(ea1.x, ea1.y), fmaxf(ea1.z, ea1.w)));
#pragma unroll
  for (int off = 32; off; off >>= 1) mx = fmaxf(mx, __shfl_xor(mx, off));
  if (lane == 0) redm[wv] = mx;
  __syncthreads();
  mx = fmaxf(fmaxf(redm[0], redm[1]), fmaxf(redm[2], redm[3]));
  ea0.x = expf(ea0.x - mx); ea0.y = expf(ea0.y - mx);
  ea0.z = expf(ea0.z - mx); ea0.w = expf(ea0.w - mx);
  ea1.x = expf(ea1.x - mx); ea1.y = expf(ea1.y - mx);
  ea1.z = expf(ea1.z - mx); ea1.w = expf(ea1.w - mx);
  float psum = ((ea0.x + ea0.y) + (ea0.z + ea0.w)) + ((ea1.x + ea1.y) + (ea1.z + ea1.w));
  float4* sc4w = (float4*)sc;
  sc4w[t] = ea0;
  sc4w[t + 256] = ea1;
#pragma unroll
  for (int off = 32; off; off >>= 1) psum += __shfl_xor(psum, off);
  if (lane == 0) reds[wv] = psum;
  __syncthreads();
  float inv = 1.0f / ((reds[0] + reds[1]) + (reds[2] + reds[3]));
  const float* vbase = v + ((size_t)b * LL * HH + h) * DD + lane;
  float acc = 0.0f;
#pragma unroll 2
  for (int base = wv * 4; base < LL; base += 16) {
    float4 p4 = sc4[base >> 2];
    acc += p4.x * vbase[(size_t)(base + 0) * ROWSTRIDE];
    acc += p4.y * vbase[(size_t)(base + 1) * ROWSTRIDE];
    acc += p4.z * vbase[(size_t)(base + 2) * ROWSTRIDE];
    acc += p4.w * vbase[(size_t)(base + 3) * ROWSTRIDE];
  }
  redp[wv][lane] = acc;
  __syncthreads();
  if (t < DD) {
    float r = (redp[0][t] + redp[1][t]) + (redp[2][t] + redp[3][t]);
    out[(((size_t)b * LL + l) * HH + h) * DD + t] = r * inv;
  }
}

extern "C" void kernel_launch(void* const* d_in, const int* in_sizes, int n_in,
                              void* d_out, int out_size, void* d_ws, size_t ws_size,
                              hipStream_t stream) {
  const float* q = (const float*)d_in[0];
  const float* k = (const float*)d_in[1];
  const float* v = (const float*)d_in[2];
  float* out = (float*)d_out;
  char* ws = (char*)d_ws;
  bool big = ws_size >= WS_NEED;

  if (big) {
    float* pm = (float*)(ws);
    float* ps = (float*)(ws + 81920);
    float* pacc = (float*)(ws + 163840);
    float* M = (float*)(ws);                  // dead before attn
    int* idx = (int*)(ws + 262144);           // dead before attn
    float* vpart = (float*)(ws);              // dead before attn
    int* mtop = (int*)(ws + 5406720);
    float* vmean = (float*)(ws + 5411840);

    k_build_idx<<<(NIDX + 255) / 256, 256, 0, stream>>>(idx);
    k_scores_M<<<BHL / 4, 256, 0, stream>>>(q, k, idx, M);
    k_topk<<<BB * HH, 256, 0, stream>>>(M, mtop);
    k_vmean_part<<<BB * HH * VCHUNKS, 256, 0, stream>>>(v, vpart);
    k_vmean_final<<<BB * HH, DD, 0, stream>>>(vpart, vmean);
    k_fill<<<(BB * LL * HH * DD / 4) / 256, 256, 0, stream>>>(vmean, out);
    k_attn_part<<<NBLK, 256, 0, stream>>>(q, k, v, mtop, pm, ps, pacc);
    k_attn_comb<<<(BB * HH * UU * 64) / 256, 256, 0, stream>>>(pm, ps, pacc, mtop, out);
  } else {
    float* M = (float*)(ws);
    int* idx = (int*)(ws + 262144);
    int* mtop = (int*)(ws + 589824);
    float* vmean = (float*)(ws + 594944);
    float* vpart = (float*)(ws);

    k_build_idx<<<(NIDX + 255) / 256, 256, 0, stream>>>(idx);
    k_scores_M<<<BHL / 4, 256, 0, stream>>>(q, k, idx, M);
    k_topk<<<BB * HH, 256, 0, stream>>>(M, mtop);
    k_vmean_part<<<BB * HH * VCHUNKS, 256, 0, stream>>>(v, vpart);
    k_vmean_final<<<BB * HH, DD, 0, stream>>>(vpart, vmean);
    k_fill<<<(BB * LL * HH * DD / 4) / 256, 256, 0, stream>>>(vmean, out);
    k_attn_mono<<<BB * HH * UU, 256, 0, stream>>>(q, k, v, mtop, out);
  }
}

// Round 7
// 178.580 us; speedup vs baseline: 4.9490x; 1.1914x over previous
//
#include <hip/hip_runtime.h>
#include <hip/hip_bf16.h>
#include <math.h>
#include <stdint.h>

// (B, L, H, D) = (4, 2048, 8, 64); FACTOR=5 => U_part = u = 40.
static constexpr int BB = 4;
static constexpr int LL = 2048;
static constexpr int HH = 8;
static constexpr int DD = 64;
static constexpr int UU = 40;
static constexpr int NSAMP = 40;
static constexpr int BHL = BB * HH * LL;   // 65536
static constexpr int NIDX = LL * NSAMP;    // 81920
static constexpr int ROWSTRIDE = HH * DD;  // 512 floats between consecutive l
static constexpr int VCHUNKS = 64;
static constexpr int NC = 16;              // KV chunks per (b,h) for split attn
static constexpr int CROWS = LL / NC;      // 128
static constexpr int NBLK = BB * HH * NC;  // 512

// ---- workspace layout (big path) ----
// pm [NBLK*UU] f32 @ 0, ps @ 81920, pacc @ 163840 (5242880) -> 5406720
// early aliases (dead before attn): M@0, idx@262144, vpart@0
// mtop @ 5406720, vmean @ 5411840 -> WS_NEED 5420032
static constexpr size_t WS_NEED = 5420032;

// ---------------- Threefry-2x32 (JAX partitionable mode) ----------------
__device__ __forceinline__ uint32_t rotl32(uint32_t x, uint32_t n) {
  return (x << n) | (x >> (32u - n));
}

__device__ __forceinline__ void tf2x32(uint32_t k0, uint32_t k1,
                                       uint32_t x0, uint32_t x1,
                                       uint32_t& o0, uint32_t& o1) {
  uint32_t ks[3] = {k0, k1, k0 ^ k1 ^ 0x1BD11BDAu};
  x0 += ks[0];
  x1 += ks[1];
  const uint32_t rotA[4] = {13u, 15u, 26u, 6u};
  const uint32_t rotB[4] = {17u, 29u, 16u, 24u};
#pragma unroll
  for (int i = 0; i < 5; ++i) {
    const uint32_t* r = (i & 1) ? rotB : rotA;
#pragma unroll
    for (int j = 0; j < 4; ++j) {
      x0 += x1;
      x1 = rotl32(x1, r[j]);
      x1 ^= x0;
    }
    x0 += ks[(i + 1) % 3];
    x1 += ks[(i + 2) % 3] + (uint32_t)(i + 1);
  }
  o0 = x0;
  o1 = x1;
}

__global__ void k_build_idx(int* __restrict__ idx) {
  int i = blockIdx.x * 256 + threadIdx.x;
  if (i >= NIDX) return;
  uint32_t ka, kb;
  tf2x32(0u, 42u, 0u, 1u, ka, kb);  // split(key(42)) -> second subkey
  uint32_t o0, o1;
  tf2x32(ka, kb, 0u, (uint32_t)i, o0, o1);
  idx[i] = (int)((o0 ^ o1) & 2047u);  // partitionable random_bits: o0^o1
}

__device__ __forceinline__ float dot4(float4 a, float4 b) {
  return a.x * b.x + a.y * b.y + a.z * b.z + a.w * b.w;
}

// M[b,h,q] = max_s - mean_s over 40 sampled dots. One wave per (b,h,q).
__global__ void k_scores_M(const float* __restrict__ q, const float* __restrict__ k,
                           const int* __restrict__ idx, float* __restrict__ M) {
  int w = (blockIdx.x * blockDim.x + threadIdx.x) >> 6;
  int lane = threadIdx.x & 63;
  if (w >= BHL) return;
  int qq = w & (LL - 1);
  int h = (w >> 11) & (HH - 1);
  int b = w >> 14;
  int rr = lane >> 3;  // sample slot within group of 8
  int dc = lane & 7;   // 8-float chunk of d
  const float* qrow = q + (((size_t)b * LL + qq) * HH + h) * DD;
  float4 q0 = ((const float4*)qrow)[dc * 2];
  float4 q1 = ((const float4*)qrow)[dc * 2 + 1];
  const float* kbase = k + ((size_t)b * LL * HH + h) * DD;
  const int* ridx = idx + qq * NSAMP;
  int kr[5];
#pragma unroll
  for (int it = 0; it < 5; ++it) kr[it] = ridx[it * 8 + rr];
  float mx = -1.0e30f, sm = 0.0f;
#pragma unroll
  for (int it = 0; it < 5; ++it) {
    const float4* kp = (const float4*)(kbase + (size_t)kr[it] * ROWSTRIDE);
    float p = dot4(q0, kp[dc * 2]) + dot4(q1, kp[dc * 2 + 1]);
    p += __shfl_xor(p, 1);
    p += __shfl_xor(p, 2);
    p += __shfl_xor(p, 4);  // reduce over dc
    mx = fmaxf(mx, p);
    sm += p;
  }
#pragma unroll
  for (int off = 8; off <= 32; off <<= 1) {  // reduce over rr
    mx = fmaxf(mx, __shfl_xor(mx, off));
    sm += __shfl_xor(sm, off);
  }
  if (lane == 0) M[w] = mx - sm * (1.0f / (float)NSAMP);
}

// Top-40 SET per (b,h) via 4-level radix-select on sortable u32 keys.
// (Output order is irrelevant: the scatter maps index l -> attention(q[l]).)
// Tie at the boundary value: lowest indices win (matches lax.top_k).
__global__ void k_topk(const float* __restrict__ M, int* __restrict__ mtop) {
  __shared__ uint32_t keys[LL];   // 8 KB
  __shared__ int hist[256];
  __shared__ int scan_res[2];     // [0]=bin, [1]=count_above
  __shared__ int nsel, neq;
  __shared__ int sel[UU];
  __shared__ int eqlist[64];
  int bh = blockIdx.x;
  int t = threadIdx.x;
  const float* m = M + (size_t)bh * LL;
  for (int i = t; i < LL; i += 256) {
    uint32_t u = __float_as_uint(m[i]);
    keys[i] = (u & 0x80000000u) ? ~u : (u | 0x80000000u);
  }
  if (t == 0) { nsel = 0; neq = 0; }
  __syncthreads();

  uint32_t prefix = 0, prefmask = 0;
  int remaining = UU;
#pragma unroll
  for (int shift = 24; shift >= 0; shift -= 8) {
    hist[t] = 0;
    __syncthreads();
    for (int i = t; i < LL; i += 256) {
      uint32_t kk = keys[i];
      if ((kk & prefmask) == prefix) atomicAdd(&hist[(kk >> shift) & 0xFF], 1);
    }
    __syncthreads();
    if (t < 64) {  // wave 0: suffix-scan over 256 bins, 4 bins/lane
      int b0 = t * 4;
      int c0 = hist[b0], c1 = hist[b0 + 1], c2 = hist[b0 + 2], c3 = hist[b0 + 3];
      int g = c0 + c1 + c2 + c3;
      int s = g;
#pragma unroll
      for (int off = 1; off < 64; off <<= 1) {
        int o = __shfl_down(s, off);
        if (t + off < 64) s += o;
      }
      int a3 = s - g;        // count in bins > b0+3
      int a2 = a3 + c3;
      int a1 = a2 + c2;
      int a0 = a1 + c1;
      if (a3 < remaining && remaining <= a3 + c3) { scan_res[0] = b0 + 3; scan_res[1] = a3; }
      if (a2 < remaining && remaining <= a2 + c2) { scan_res[0] = b0 + 2; scan_res[1] = a2; }
      if (a1 < remaining && remaining <= a1 + c1) { scan_res[0] = b0 + 1; scan_res[1] = a1; }
      if (a0 < remaining && remaining <= a0 + c0) { scan_res[0] = b0 + 0; scan_res[1] = a0; }
    }
    __syncthreads();
    prefix |= ((uint32_t)scan_res[0] << shift);
    prefmask |= (0xFFu << shift);
    remaining -= scan_res[1];
    __syncthreads();
  }

  uint32_t T = prefix;  // exact key of boundary element
  for (int i = t; i < LL; i += 256) {
    uint32_t kk = keys[i];
    if (kk > T) {
      int p = atomicAdd(&nsel, 1);
      sel[p] = i;
    } else if (kk == T) {
      int p = atomicAdd(&neq, 1);
      if (p < 64) eqlist[p] = i;
    }
  }
  __syncthreads();
  if (t == 0) {
    int need = UU - nsel;  // == remaining
    int count = neq < 64 ? neq : 64;
    for (int r = 0; r < need; ++r) {
      int mn = 1 << 30, mpos = 0;
      for (int e = 0; e < count; ++e)
        if (eqlist[e] < mn) { mn = eqlist[e]; mpos = e; }
      sel[nsel + r] = mn;
      eqlist[mpos] = 1 << 30;
    }
  }
  __syncthreads();
  if (t < UU) mtop[bh * UU + t] = sel[t];
}

// V_mean phase 1: 2048 blocks; each sums 32 rows of one (b,h).
__global__ void k_vmean_part(const float* __restrict__ v, float* __restrict__ partial) {
  __shared__ float part[4][DD];
  int bid = blockIdx.x;
  int bh = bid >> 6;
  int chunk = bid & 63;
  int b = bh >> 3, h = bh & 7;
  int t = threadIdx.x;
  int wv = t >> 6, lane = t & 63;
  int l0 = chunk * (LL / VCHUNKS);
  const float* base = v + ((size_t)b * LL * HH + h) * DD + lane;
  float s = 0.0f;
#pragma unroll
  for (int r = wv; r < LL / VCHUNKS; r += 4) s += base[(size_t)(l0 + r) * ROWSTRIDE];
  part[wv][lane] = s;
  __syncthreads();
  if (t < DD) {
    partial[(size_t)bid * DD + t] =
        (part[0][t] + part[1][t]) + (part[2][t] + part[3][t]);
  }
}

__global__ void k_vmean_final(const float* __restrict__ partial, float* __restrict__ vmean) {
  int bh = blockIdx.x;
  int d = threadIdx.x;
  const float* p = partial + (size_t)bh * VCHUNKS * DD + d;
  float s = 0.0f;
#pragma unroll
  for (int c = 0; c < VCHUNKS; ++c) s += p[(size_t)c * DD];
  vmean[bh * DD + d] = s * (1.0f / (float)LL);
}

__global__ void k_fill(const float* __restrict__ vmean, float* __restrict__ out) {
  int f = blockIdx.x * 256 + threadIdx.x;
  int d4 = f & 15;
  int h = (f >> 4) & 7;
  int b = f >> 18;
  ((float4*)out)[f] = ((const float4*)vmean)[(((b << 3) + h) << 4) + d4];
}

// ---- split-KV attention, phase 1: block = (bh, chunk of 128 K rows) ----
__global__ void __launch_bounds__(256)
k_attn_part(const float* __restrict__ q, const float* __restrict__ k,
            const float* __restrict__ v, const int* __restrict__ mtop,
            float* __restrict__ pm, float* __restrict__ ps,
            float* __restrict__ pacc) {
  __shared__ float qs[UU][DD];      // 10 KB
  __shared__ float sc[UU][CROWS];   // 20 KB
  int blk = blockIdx.x;             // bh*NC + c
  int c = blk & (NC - 1);
  int bh = blk >> 4;
  int b = bh >> 3, h = bh & 7;
  int t = threadIdx.x;
  int wv = t >> 6, lane = t & 63;
  int l0 = c * CROWS;

  for (int i = t; i < UU * DD; i += 256) {
    int j = i >> 6, d = i & 63;
    int l = mtop[bh * UU + j];
    qs[j][d] = q[(((size_t)b * LL + l) * HH + h) * DD + d];
  }
  __syncthreads();

  const float* kbase = k + ((size_t)b * LL * HH + h) * DD;

  int rr = lane & 15, dcq = lane >> 4;
  float4 kv0[4], kv1[4];
  {
    const float* kr0 = kbase + (size_t)(l0 + wv * 32 + rr) * ROWSTRIDE + dcq * 16;
    const float* kr1 = kbase + (size_t)(l0 + wv * 32 + 16 + rr) * ROWSTRIDE + dcq * 16;
#pragma unroll
    for (int i = 0; i < 4; ++i) {
      kv0[i] = *(const float4*)(kr0 + i * 4);
      kv1[i] = *(const float4*)(kr1 + i * 4);
    }
  }
#pragma unroll 4
  for (int j = 0; j < UU; ++j) {
    const float* qp = &qs[j][dcq * 16];
    float4 qa = *(const float4*)(qp);
    float4 qb = *(const float4*)(qp + 4);
    float4 qc = *(const float4*)(qp + 8);
    float4 qd = *(const float4*)(qp + 12);
    float p0 = dot4(qa, kv0[0]) + dot4(qb, kv0[1]) + dot4(qc, kv0[2]) + dot4(qd, kv0[3]);
    float p1 = dot4(qa, kv1[0]) + dot4(qb, kv1[1]) + dot4(qc, kv1[2]) + dot4(qd, kv1[3]);
    p0 += __shfl_xor(p0, 16);
    p0 += __shfl_xor(p0, 32);
    p1 += __shfl_xor(p1, 16);
    p1 += __shfl_xor(p1, 32);
    if (lane < 16) {
      sc[j][wv * 32 + lane] = p0 * 0.125f;
      sc[j][wv * 32 + 16 + lane] = p1 * 0.125f;
    }
  }
  __syncthreads();

#pragma unroll
  for (int jj = 0; jj < 10; ++jj) {
    int j = wv * 10 + jj;
    float a0 = sc[j][lane];
    float a1 = sc[j][lane + 64];
    float mx = fmaxf(a0, a1);
#pragma unroll
    for (int off = 32; off; off >>= 1) mx = fmaxf(mx, __shfl_xor(mx, off));
    float e0 = expf(a0 - mx), e1 = expf(a1 - mx);
    sc[j][lane] = e0;
    sc[j][lane + 64] = e1;
    float s = e0 + e1;
#pragma unroll
    for (int off = 32; off; off >>= 1) s += __shfl_xor(s, off);
    if (lane == 0) {
      pm[(size_t)blk * UU + j] = mx;
      ps[(size_t)blk * UU + j] = s;
    }
  }

  const float* vbase = v + ((size_t)b * LL * HH + h) * DD + lane;
  float acc[10];
#pragma unroll
  for (int jj = 0; jj < 10; ++jj) acc[jj] = 0.0f;
  for (int r = 0; r < CROWS; r += 4) {
    float v0 = vbase[(size_t)(l0 + r + 0) * ROWSTRIDE];
    float v1 = vbase[(size_t)(l0 + r + 1) * ROWSTRIDE];
    float v2 = vbase[(size_t)(l0 + r + 2) * ROWSTRIDE];
    float v3 = vbase[(size_t)(l0 + r + 3) * ROWSTRIDE];
#pragma unroll
    for (int jj = 0; jj < 10; ++jj) {
      int j = wv * 10 + jj;
      float4 p4 = *(const float4*)&sc[j][r];
      acc[jj] += p4.x * v0 + p4.y * v1 + p4.z * v2 + p4.w * v3;
    }
  }
#pragma unroll
  for (int jj = 0; jj < 10; ++jj) {
    int j = wv * 10 + jj;
    pacc[((size_t)blk * UU + j) * DD + lane] = acc[jj];
  }
}

// ---- split-KV attention, phase 2: one wave per (bh, j) combines 16 chunks ----
__global__ void k_attn_comb(const float* __restrict__ pm, const float* __restrict__ ps,
                            const float* __restrict__ pacc, const int* __restrict__ mtop,
                            float* __restrict__ out) {
  int wid = (blockIdx.x * 256 + threadIdx.x) >> 6;
  int lane = threadIdx.x & 63;
  if (wid >= BB * HH * UU) return;
  int j = wid % UU;
  int bh = wid / UU;
  int b = bh >> 3, h = bh & 7;
  float mv = (lane < NC) ? pm[((size_t)(bh * NC + lane)) * UU + j] : -1.0e30f;
  float mx = mv;
#pragma unroll
  for (int off = 8; off; off >>= 1) mx = fmaxf(mx, __shfl_xor(mx, off));
  mx = __shfl(mx, 0);
  float e = (lane < NC) ? expf(mv - mx) : 0.0f;
  float sv = (lane < NC) ? ps[((size_t)(bh * NC + lane)) * UU + j] * e : 0.0f;
  float st = sv;
#pragma unroll
  for (int off = 8; off; off >>= 1) st += __shfl_xor(st, off);
  st = __shfl(st, 0);
  float a = 0.0f;
#pragma unroll
  for (int c = 0; c < NC; ++c) {
    float ec = __shfl(e, c);
    a += ec * pacc[((size_t)(bh * NC + c) * UU + j) * DD + lane];
  }
  int l = mtop[bh * UU + j];
  out[(((size_t)b * LL + l) * HH + h) * DD + lane] = a / st;
}

// ---- fallback mono attention (small-ws path) ----
__global__ void k_attn_mono(const float* __restrict__ q, const float* __restrict__ k,
                            const float* __restrict__ v, const int* __restrict__ mtop,
                            float* __restrict__ out) {
  __shared__ float sc[LL];
  __shared__ float redm[4];
  __shared__ float reds[4];
  __shared__ float redp[4][DD];
  int blk = blockIdx.x;
  int j = blk % UU;
  int bh = blk / UU;
  int b = bh >> 3, h = bh & 7;
  int l = mtop[bh * UU + j];
  int t = threadIdx.x;
  int wv = t >> 6, lane = t & 63;
  int dc = t & 15, r2 = (t >> 4) & 3;
  const float4* qrow = (const float4*)(q + (((size_t)b * LL + l) * HH + h) * DD);
  float4 qv = qrow[dc];
  const float* kbase = k + ((size_t)b * LL * HH + h) * DD;
#pragma unroll 4
  for (int base = wv * 4; base < LL; base += 16) {
    int row = base + r2;
    const float4* krow = (const float4*)(kbase + (size_t)row * ROWSTRIDE);
    float4 kv = krow[dc];
    float p = dot4(qv, kv);
    p += __shfl_xor(p, 1);
    p += __shfl_xor(p, 2);
    p += __shfl_xor(p, 4);
    p += __shfl_xor(p, 8);
    if (dc == 0) sc[row] = p * 0.125f;
  }
  __syncthreads();
  const float4* sc4 = (const float4*)sc;
  float4 ea0 = sc4[t];
  float4 ea1 = sc4[t + 256];
  float mx = fmaxf(fmaxf(fmaxf(ea0.x, ea0.y), fmaxf(ea0.z, ea0.w)),
                   fmaxf(fmaxf(ea1.x, ea1.y), fmaxf(ea1.z, ea1.w)));
#pragma unroll
  for (int off = 32; off; off >>= 1) mx = fmaxf(mx, __shfl_xor(mx, off));
  if (lane == 0) redm[wv] = mx;
  __syncthreads();
  mx = fmaxf(fmaxf(redm[0], redm[1]), fmaxf(redm[2], redm[3]));
  ea0.x = expf(ea0.x - mx); ea0.y = expf(ea0.y - mx);
  ea0.z = expf(ea0.z - mx); ea0.w = expf(ea0.w - mx);
  ea1.x = expf(ea1.x - mx); ea1.y = expf(ea1.y - mx);
  ea1.z = expf(ea1.z - mx); ea1.w = expf(ea1.w - mx);
  float psum = ((ea0.x + ea0.y) + (ea0.z + ea0.w)) + ((ea1.x + ea1.y) + (ea1.z + ea1.w));
  float4* sc4w = (float4*)sc;
  sc4w[t] = ea0;
  sc4w[t + 256] = ea1;
#pragma unroll
  for (int off = 32; off; off >>= 1) psum += __shfl_xor(psum, off);
  if (lane == 0) reds[wv] = psum;
  __syncthreads();
  float inv = 1.0f / ((reds[0] + reds[1]) + (reds[2] + reds[3]));
  const float* vbase = v + ((size_t)b * LL * HH + h) * DD + lane;
  float acc = 0.0f;
#pragma unroll 2
  for (int base = wv * 4; base < LL; base += 16) {
    float4 p4 = sc4[base >> 2];
    acc += p4.x * vbase[(size_t)(base + 0) * ROWSTRIDE];
    acc += p4.y * vbase[(size_t)(base + 1) * ROWSTRIDE];
    acc += p4.z * vbase[(size_t)(base + 2) * ROWSTRIDE];
    acc += p4.w * vbase[(size_t)(base + 3) * ROWSTRIDE];
  }
  redp[wv][lane] = acc;
  __syncthreads();
  if (t < DD) {
    float r = (redp[0][t] + redp[1][t]) + (redp[2][t] + redp[3][t]);
    out[(((size_t)b * LL + l) * HH + h) * DD + t] = r * inv;
  }
}

extern "C" void kernel_launch(void* const* d_in, const int* in_sizes, int n_in,
                              void* d_out, int out_size, void* d_ws, size_t ws_size,
                              hipStream_t stream) {
  const float* q = (const float*)d_in[0];
  const float* k = (const float*)d_in[1];
  const float* v = (const float*)d_in[2];
  float* out = (float*)d_out;
  char* ws = (char*)d_ws;
  bool big = ws_size >= WS_NEED;

  if (big) {
    float* pm = (float*)(ws);
    float* ps = (float*)(ws + 81920);
    float* pacc = (float*)(ws + 163840);
    float* M = (float*)(ws);                  // dead before attn
    int* idx = (int*)(ws + 262144);           // dead before attn
    float* vpart = (float*)(ws);              // dead before attn
    int* mtop = (int*)(ws + 5406720);
    float* vmean = (float*)(ws + 5411840);

    k_build_idx<<<(NIDX + 255) / 256, 256, 0, stream>>>(idx);
    k_scores_M<<<BHL / 4, 256, 0, stream>>>(q, k, idx, M);
    k_topk<<<BB * HH, 256, 0, stream>>>(M, mtop);
    k_vmean_part<<<BB * HH * VCHUNKS, 256, 0, stream>>>(v, vpart);
    k_vmean_final<<<BB * HH, DD, 0, stream>>>(vpart, vmean);
    k_fill<<<(BB * LL * HH * DD / 4) / 256, 256, 0, stream>>>(vmean, out);
    k_attn_part<<<NBLK, 256, 0, stream>>>(q, k, v, mtop, pm, ps, pacc);
    k_attn_comb<<<(BB * HH * UU * 64) / 256, 256, 0, stream>>>(pm, ps, pacc, mtop, out);
  } else {
    float* M = (float*)(ws);
    int* idx = (int*)(ws + 262144);
    int* mtop = (int*)(ws + 589824);
    float* vmean = (float*)(ws + 594944);
    float* vpart = (float*)(ws);

    k_build_idx<<<(NIDX + 255) / 256, 256, 0, stream>>>(idx);
    k_scores_M<<<BHL / 4, 256, 0, stream>>>(q, k, idx, M);
    k_topk<<<BB * HH, 256, 0, stream>>>(M, mtop);
    k_vmean_part<<<BB * HH * VCHUNKS, 256, 0, stream>>>(v, vpart);
    k_vmean_final<<<BB * HH, DD, 0, stream>>>(vpart, vmean);
    k_fill<<<(BB * LL * HH * DD / 4) / 256, 256, 0, stream>>>(vmean, out);
    k_attn_mono<<<BB * HH * UU, 256, 0, stream>>>(q, k, v, mtop, out);
  }
}

// Round 9
// 177.154 us; speedup vs baseline: 4.9888x; 1.0081x over previous
//
#include <hip/hip_runtime.h>
#include <hip/hip_bf16.h>
#include <math.h>
#include <stdint.h>

// (B, L, H, D) = (4, 2048, 8, 64); FACTOR=5 => U_part = u = 40.
static constexpr int BB = 4;
static constexpr int LL = 2048;
static constexpr int HH = 8;
static constexpr int DD = 64;
static constexpr int UU = 40;
static constexpr int NSAMP = 40;
static constexpr int BHL = BB * HH * LL;   // 65536
static constexpr int ROWSTRIDE = HH * DD;  // 512
static constexpr int VCHUNKS = 64;
static constexpr int NC = 32;              // KV chunks per (b,h) for split attn
static constexpr int CROWS = LL / NC;      // 64
static constexpr int NBLK = BB * HH * NC;  // 1024

// ---- workspace layout (big path) ----
// pm [NBLK*UU] @0 (163840), ps @163840 (163840), pacc @327680 (10485760) -> 10813440
// early aliases in [0,10813440): M@0 (262144, dead after topk), vpart@0 (524288,
// written after topk, dead after vmean_final)
// mtop @10813440 (5120), vmean @10818560 (8192) -> WS_NEED 10826752
static constexpr size_t WS_NEED = 10826752;

// ---------------- Threefry-2x32 (JAX partitionable mode) ----------------
__device__ __forceinline__ uint32_t rotl32(uint32_t x, uint32_t n) {
  return (x << n) | (x >> (32u - n));
}

__device__ __forceinline__ void tf2x32(uint32_t k0, uint32_t k1,
                                       uint32_t x0, uint32_t x1,
                                       uint32_t& o0, uint32_t& o1) {
  uint32_t ks[3] = {k0, k1, k0 ^ k1 ^ 0x1BD11BDAu};
  x0 += ks[0];
  x1 += ks[1];
  const uint32_t rotA[4] = {13u, 15u, 26u, 6u};
  const uint32_t rotB[4] = {17u, 29u, 16u, 24u};
#pragma unroll
  for (int i = 0; i < 5; ++i) {
    const uint32_t* r = (i & 1) ? rotB : rotA;
#pragma unroll
    for (int j = 0; j < 4; ++j) {
      x0 += x1;
      x1 = rotl32(x1, r[j]);
      x1 ^= x0;
    }
    x0 += ks[(i + 1) % 3];
    x1 += ks[(i + 2) % 3] + (uint32_t)(i + 1);
  }
  o0 = x0;
  o1 = x1;
}

__device__ __forceinline__ float dot4(float4 a, float4 b) {
  return a.x * b.x + a.y * b.y + a.z * b.z + a.w * b.w;
}

// M[b,h,q] = max_s - mean_s over 40 sampled dots. One wave per (b,h,q).
// Threefry fused (lanes 0..39 hash their sample; broadcast via shfl).
// XCD-swizzled block remap: each XCD gets 4 contiguous (b,h) -> K fits its L2.
__global__ void k_scores_M(const float* __restrict__ q, const float* __restrict__ k,
                           float* __restrict__ M) {
  const int NWG = BHL / 4;  // 16384 blocks, 16384 % 8 == 0 -> bijective swizzle
  int wg = (blockIdx.x & 7) * (NWG / 8) + (blockIdx.x >> 3);
  int w = wg * 4 + (threadIdx.x >> 6);
  int lane = threadIdx.x & 63;
  int qq = w & (LL - 1);
  int h = (w >> 11) & (HH - 1);
  int b = w >> 14;

  // sample indices: idx[i] for i = qq*40 + lane  (partitionable: o0^o1 % 2048)
  uint32_t ka, kb;
  tf2x32(0u, 42u, 0u, 1u, ka, kb);  // constant-folds
  uint32_t o0, o1;
  tf2x32(ka, kb, 0u, (uint32_t)(qq * NSAMP + lane), o0, o1);
  int idxv = (int)((o0 ^ o1) & 2047u);

  int rr = lane >> 3;  // sample slot within group of 8
  int dc = lane & 7;   // 8-float chunk of d
  const float* qrow = q + (((size_t)b * LL + qq) * HH + h) * DD;
  float4 q0 = ((const float4*)qrow)[dc * 2];
  float4 q1 = ((const float4*)qrow)[dc * 2 + 1];
  const float* kbase = k + ((size_t)b * LL * HH + h) * DD;
  int kr[5];
#pragma unroll
  for (int it = 0; it < 5; ++it) kr[it] = __shfl(idxv, it * 8 + rr);
  float mx = -1.0e30f, sm = 0.0f;
#pragma unroll
  for (int it = 0; it < 5; ++it) {
    const float4* kp = (const float4*)(kbase + (size_t)kr[it] * ROWSTRIDE);
    float p = dot4(q0, kp[dc * 2]) + dot4(q1, kp[dc * 2 + 1]);
    p += __shfl_xor(p, 1);
    p += __shfl_xor(p, 2);
    p += __shfl_xor(p, 4);  // reduce over dc
    mx = fmaxf(mx, p);
    sm += p;
  }
#pragma unroll
  for (int off = 8; off <= 32; off <<= 1) {  // reduce over rr
    mx = fmaxf(mx, __shfl_xor(mx, off));
    sm += __shfl_xor(sm, off);
  }
  if (lane == 0) M[w] = mx - sm * (1.0f / (float)NSAMP);
}

// Top-40 SET per (b,h) via radix-select (order-free; boundary ties -> lowest idx).
__global__ void k_topk(const float* __restrict__ M, int* __restrict__ mtop) {
  __shared__ uint32_t keys[LL];
  __shared__ int hist[256];
  __shared__ int scan_res[2];
  __shared__ int nsel, neq;
  __shared__ int sel[UU];
  __shared__ int eqlist[64];
  int bh = blockIdx.x;
  int t = threadIdx.x;
  const float* m = M + (size_t)bh * LL;
  for (int i = t; i < LL; i += 256) {
    uint32_t u = __float_as_uint(m[i]);
    keys[i] = (u & 0x80000000u) ? ~u : (u | 0x80000000u);
  }
  if (t == 0) { nsel = 0; neq = 0; }
  __syncthreads();

  uint32_t prefix = 0, prefmask = 0;
  int remaining = UU;
#pragma unroll
  for (int shift = 24; shift >= 0; shift -= 8) {
    hist[t] = 0;
    __syncthreads();
    for (int i = t; i < LL; i += 256) {
      uint32_t kk = keys[i];
      if ((kk & prefmask) == prefix) atomicAdd(&hist[(kk >> shift) & 0xFF], 1);
    }
    __syncthreads();
    if (t < 64) {
      int b0 = t * 4;
      int c0 = hist[b0], c1 = hist[b0 + 1], c2 = hist[b0 + 2], c3 = hist[b0 + 3];
      int g = c0 + c1 + c2 + c3;
      int s = g;
#pragma unroll
      for (int off = 1; off < 64; off <<= 1) {
        int o = __shfl_down(s, off);
        if (t + off < 64) s += o;
      }
      int a3 = s - g;
      int a2 = a3 + c3;
      int a1 = a2 + c2;
      int a0 = a1 + c1;
      if (a3 < remaining && remaining <= a3 + c3) { scan_res[0] = b0 + 3; scan_res[1] = a3; }
      if (a2 < remaining && remaining <= a2 + c2) { scan_res[0] = b0 + 2; scan_res[1] = a2; }
      if (a1 < remaining && remaining <= a1 + c1) { scan_res[0] = b0 + 1; scan_res[1] = a1; }
      if (a0 < remaining && remaining <= a0 + c0) { scan_res[0] = b0 + 0; scan_res[1] = a0; }
    }
    __syncthreads();
    prefix |= ((uint32_t)scan_res[0] << shift);
    prefmask |= (0xFFu << shift);
    remaining -= scan_res[1];
    __syncthreads();
  }

  uint32_t T = prefix;
  for (int i = t; i < LL; i += 256) {
    uint32_t kk = keys[i];
    if (kk > T) {
      int p = atomicAdd(&nsel, 1);
      sel[p] = i;
    } else if (kk == T) {
      int p = atomicAdd(&neq, 1);
      if (p < 64) eqlist[p] = i;
    }
  }
  __syncthreads();
  if (t == 0) {
    int need = UU - nsel;
    int count = neq < 64 ? neq : 64;
    for (int r = 0; r < need; ++r) {
      int mn = 1 << 30, mpos = 0;
      for (int e = 0; e < count; ++e)
        if (eqlist[e] < mn) { mn = eqlist[e]; mpos = e; }
      sel[nsel + r] = mn;
      eqlist[mpos] = 1 << 30;
    }
  }
  __syncthreads();
  if (t < UU) mtop[bh * UU + t] = sel[t];
}

// V_mean phase 1: 2048 blocks; each sums 32 rows of one (b,h).
__global__ void k_vmean_part(const float* __restrict__ v, float* __restrict__ partial) {
  __shared__ float part[4][DD];
  int bid = blockIdx.x;
  int bh = bid >> 6;
  int chunk = bid & 63;
  int b = bh >> 3, h = bh & 7;
  int t = threadIdx.x;
  int wv = t >> 6, lane = t & 63;
  int l0 = chunk * (LL / VCHUNKS);
  const float* base = v + ((size_t)b * LL * HH + h) * DD + lane;
  float s = 0.0f;
#pragma unroll
  for (int r = wv; r < LL / VCHUNKS; r += 4) s += base[(size_t)(l0 + r) * ROWSTRIDE];
  part[wv][lane] = s;
  __syncthreads();
  if (t < DD) {
    partial[(size_t)bid * DD + t] =
        (part[0][t] + part[1][t]) + (part[2][t] + part[3][t]);
  }
}

__global__ void k_vmean_final(const float* __restrict__ partial, float* __restrict__ vmean) {
  int bh = blockIdx.x;
  int d = threadIdx.x;
  const float* p = partial + (size_t)bh * VCHUNKS * DD + d;
  float s = 0.0f;
#pragma unroll
  for (int c = 0; c < VCHUNKS; ++c) s += p[(size_t)c * DD];
  vmean[bh * DD + d] = s * (1.0f / (float)LL);
}

__global__ void k_fill(const float* __restrict__ vmean, float* __restrict__ out) {
  int f = blockIdx.x * 256 + threadIdx.x;
  int d4 = f & 15;
  int h = (f >> 4) & 7;
  int b = f >> 18;
  ((float4*)out)[f] = ((const float4*)vmean)[(((b << 3) + h) << 4) + d4];
}

// ---- split-KV attention, phase 1: block = (bh, chunk of 64 K rows) ----
__global__ void __launch_bounds__(256)
k_attn_part(const float* __restrict__ q, const float* __restrict__ k,
            const float* __restrict__ v, const int* __restrict__ mtop,
            float* __restrict__ pm, float* __restrict__ ps,
            float* __restrict__ pacc) {
  __shared__ float qs[UU][DD];      // 10 KB
  __shared__ float sc[UU][CROWS];   // 10 KB
  int blk = blockIdx.x;             // bh*NC + c
  int c = blk & (NC - 1);
  int bh = blk >> 5;
  int b = bh >> 3, h = bh & 7;
  int t = threadIdx.x;
  int wv = t >> 6, lane = t & 63;
  int l0 = c * CROWS;

  for (int i = t; i < UU * DD; i += 256) {
    int j = i >> 6, d = i & 63;
    int l = mtop[bh * UU + j];
    qs[j][d] = q[(((size_t)b * LL + l) * HH + h) * DD + d];
  }
  __syncthreads();

  const float* kbase = k + ((size_t)b * LL * HH + h) * DD;

  // wave holds 16 K rows (lane = (rr row, dcq d-quarter of 16 floats))
  int rr = lane & 15, dcq = lane >> 4;
  float4 kv0[4];
  {
    const float* kr0 = kbase + (size_t)(l0 + wv * 16 + rr) * ROWSTRIDE + dcq * 16;
#pragma unroll
    for (int i = 0; i < 4; ++i) kv0[i] = *(const float4*)(kr0 + i * 4);
  }
#pragma unroll 4
  for (int j = 0; j < UU; ++j) {
    const float* qp = &qs[j][dcq * 16];
    float4 qa = *(const float4*)(qp);
    float4 qb = *(const float4*)(qp + 4);
    float4 qc = *(const float4*)(qp + 8);
    float4 qd = *(const float4*)(qp + 12);
    float p0 = dot4(qa, kv0[0]) + dot4(qb, kv0[1]) + dot4(qc, kv0[2]) + dot4(qd, kv0[3]);
    p0 += __shfl_xor(p0, 16);
    p0 += __shfl_xor(p0, 32);
    if (lane < 16) sc[j][wv * 16 + lane] = p0 * 0.125f;
  }
  __syncthreads();

  // per-query chunk max + exp + sum (wave owns 10 queries; 64 rows = 64 lanes)
#pragma unroll
  for (int jj = 0; jj < 10; ++jj) {
    int j = wv * 10 + jj;
    float a0 = sc[j][lane];
    float mx = a0;
#pragma unroll
    for (int off = 32; off; off >>= 1) mx = fmaxf(mx, __shfl_xor(mx, off));
    float e0 = expf(a0 - mx);
    sc[j][lane] = e0;
    float s = e0;
#pragma unroll
    for (int off = 32; off; off >>= 1) s += __shfl_xor(s, off);
    if (lane == 0) {
      pm[(size_t)blk * UU + j] = mx;
      ps[(size_t)blk * UU + j] = s;
    }
  }

  const float* vbase = v + ((size_t)b * LL * HH + h) * DD + lane;
  float acc[10];
#pragma unroll
  for (int jj = 0; jj < 10; ++jj) acc[jj] = 0.0f;
  for (int r = 0; r < CROWS; r += 4) {
    float v0 = vbase[(size_t)(l0 + r + 0) * ROWSTRIDE];
    float v1 = vbase[(size_t)(l0 + r + 1) * ROWSTRIDE];
    float v2 = vbase[(size_t)(l0 + r + 2) * ROWSTRIDE];
    float v3 = vbase[(size_t)(l0 + r + 3) * ROWSTRIDE];
#pragma unroll
    for (int jj = 0; jj < 10; ++jj) {
      int j = wv * 10 + jj;
      float4 p4 = *(const float4*)&sc[j][r];
      acc[jj] += p4.x * v0 + p4.y * v1 + p4.z * v2 + p4.w * v3;
    }
  }
#pragma unroll
  for (int jj = 0; jj < 10; ++jj) {
    int j = wv * 10 + jj;
    pacc[((size_t)blk * UU + j) * DD + lane] = acc[jj];
  }
}

// ---- split-KV attention, phase 2: one wave per (bh, j) combines 32 chunks ----
__global__ void k_attn_comb(const float* __restrict__ pm, const float* __restrict__ ps,
                            const float* __restrict__ pacc, const int* __restrict__ mtop,
                            float* __restrict__ out) {
  int wid = (blockIdx.x * 256 + threadIdx.x) >> 6;
  int lane = threadIdx.x & 63;
  if (wid >= BB * HH * UU) return;
  int j = wid % UU;
  int bh = wid / UU;
  int b = bh >> 3, h = bh & 7;
  float mv = (lane < NC) ? pm[((size_t)(bh * NC + lane)) * UU + j] : -1.0e30f;
  float mx = mv;
#pragma unroll
  for (int off = 16; off; off >>= 1) mx = fmaxf(mx, __shfl_xor(mx, off));
  mx = __shfl(mx, 0);
  float e = (lane < NC) ? expf(mv - mx) : 0.0f;
  float sv = (lane < NC) ? ps[((size_t)(bh * NC + lane)) * UU + j] * e : 0.0f;
  float st = sv;
#pragma unroll
  for (int off = 16; off; off >>= 1) st += __shfl_xor(st, off);
  st = __shfl(st, 0);
  float a = 0.0f;
#pragma unroll
  for (int c = 0; c < NC; ++c) {
    float ec = __shfl(e, c);
    a += ec * pacc[((size_t)(bh * NC + c) * UU + j) * DD + lane];
  }
  int l = mtop[bh * UU + j];
  out[(((size_t)b * LL + l) * HH + h) * DD + lane] = a / st;
}

// ---- fallback mono attention (small-ws path) ----
__global__ void k_attn_mono(const float* __restrict__ q, const float* __restrict__ k,
                            const float* __restrict__ v, const int* __restrict__ mtop,
                            float* __restrict__ out) {
  __shared__ float sc[LL];
  __shared__ float redm[4];
  __shared__ float reds[4];
  __shared__ float redp[4][DD];
  int blk = blockIdx.x;
  int j = blk % UU;
  int bh = blk / UU;
  int b = bh >> 3, h = bh & 7;
  int l = mtop[bh * UU + j];
  int t = threadIdx.x;
  int wv = t >> 6, lane = t & 63;
  int dc = t & 15, r2 = (t >> 4) & 3;
  const float4* qrow = (const float4*)(q + (((size_t)b * LL + l) * HH + h) * DD);
  float4 qv = qrow[dc];
  const float* kbase = k + ((size_t)b * LL * HH + h) * DD;
#pragma unroll 4
  for (int base = wv * 4; base < LL; base += 16) {
    int row = base + r2;
    const float4* krow = (const float4*)(kbase + (size_t)row * ROWSTRIDE);
    float4 kv = krow[dc];
    float p = dot4(qv, kv);
    p += __shfl_xor(p, 1);
    p += __shfl_xor(p, 2);
    p += __shfl_xor(p, 4);
    p += __shfl_xor(p, 8);
    if (dc == 0) sc[row] = p * 0.125f;
  }
  __syncthreads();
  const float4* sc4 = (const float4*)sc;
  float4 ea0 = sc4[t];
  float4 ea1 = sc4[t + 256];
  float mx = fmaxf(fmaxf(fmaxf(ea0.x, ea0.y), fmaxf(ea0.z, ea0.w)),
                   fmaxf(fmaxf(ea1.x, ea1.y), fmaxf(ea1.z, ea1.w)));
#pragma unroll
  for (int off = 32; off; off >>= 1) mx = fmaxf(mx, __shfl_xor(mx, off));
  if (lane == 0) redm[wv] = mx;
  __syncthreads();
  mx = fmaxf(fmaxf(redm[0], redm[1]), fmaxf(redm[2], redm[3]));
  ea0.x = expf(ea0.x - mx); ea0.y = expf(ea0.y - mx);
  ea0.z = expf(ea0.z - mx); ea0.w = expf(ea0.w - mx);
  ea1.x = expf(ea1.x - mx); ea1.y = expf(ea1.y - mx);
  ea1.z = expf(ea1.z - mx); ea1.w = expf(ea1.w - mx);
  float psum = ((ea0.x + ea0.y) + (ea0.z + ea0.w)) + ((ea1.x + ea1.y) + (ea1.z + ea1.w));
  float4* sc4w = (float4*)sc;
  sc4w[t] = ea0;
  sc4w[t + 256] = ea1;
#pragma unroll
  for (int off = 32; off; off >>= 1) psum += __shfl_xor(psum, off);
  if (lane == 0) reds[wv] = psum;
  __syncthreads();
  float inv = 1.0f / ((reds[0] + reds[1]) + (reds[2] + reds[3]));
  const float* vbase = v + ((size_t)b * LL * HH + h) * DD + lane;
  float acc = 0.0f;
#pragma unroll 2
  for (int base = wv * 4; base < LL; base += 16) {
    float4 p4 = sc4[base >> 2];
    acc += p4.x * vbase[(size_t)(base + 0) * ROWSTRIDE];
    acc += p4.y * vbase[(size_t)(base + 1) * ROWSTRIDE];
    acc += p4.z * vbase[(size_t)(base + 2) * ROWSTRIDE];
    acc += p4.w * vbase[(size_t)(base + 3) * ROWSTRIDE];
  }
  redp[wv][lane] = acc;
  __syncthreads();
  if (t < DD) {
    float r = (redp[0][t] + redp[1][t]) + (redp[2][t] + redp[3][t]);
    out[(((size_t)b * LL + l) * HH + h) * DD + t] = r * inv;
  }
}

extern "C" void kernel_launch(void* const* d_in, const int* in_sizes, int n_in,
                              void* d_out, int out_size, void* d_ws, size_t ws_size,
                              hipStream_t stream) {
  const float* q = (const float*)d_in[0];
  const float* k = (const float*)d_in[1];
  const float* v = (const float*)d_in[2];
  float* out = (float*)d_out;
  char* ws = (char*)d_ws;
  bool big = ws_size >= WS_NEED;

  if (big) {
    float* pm = (float*)(ws);
    float* ps = (float*)(ws + 163840);
    float* pacc = (float*)(ws + 327680);
    float* M = (float*)(ws);                  // dead after k_topk
    float* vpart = (float*)(ws);              // lives topk..vmean_final
    int* mtop = (int*)(ws + 10813440);
    float* vmean = (float*)(ws + 10818560);

    k_scores_M<<<BHL / 4, 256, 0, stream>>>(q, k, M);
    k_topk<<<BB * HH, 256, 0, stream>>>(M, mtop);
    k_vmean_part<<<BB * HH * VCHUNKS, 256, 0, stream>>>(v, vpart);
    k_vmean_final<<<BB * HH, DD, 0, stream>>>(vpart, vmean);
    k_fill<<<(BB * LL * HH * DD / 4) / 256, 256, 0, stream>>>(vmean, out);
    k_attn_part<<<NBLK, 256, 0, stream>>>(q, k, v, mtop, pm, ps, pacc);
    k_attn_comb<<<(BB * HH * UU * 64) / 256, 256, 0, stream>>>(pm, ps, pacc, mtop, out);
  } else {
    float* M = (float*)(ws);                  // @0, 262144; dead after topk
    float* vpart = (float*)(ws);              // @0, 524288; after topk
    int* mtop = (int*)(ws + 524288);
    float* vmean = (float*)(ws + 529408);

    k_scores_M<<<BHL / 4, 256, 0, stream>>>(q, k, M);
    k_topk<<<BB * HH, 256, 0, stream>>>(M, mtop);
    k_vmean_part<<<BB * HH * VCHUNKS, 256, 0, stream>>>(v, vpart);
    k_vmean_final<<<BB * HH, DD, 0, stream>>>(vpart, vmean);
    k_fill<<<(BB * LL * HH * DD / 4) / 256, 256, 0, stream>>>(vmean, out);
    k_attn_mono<<<BB * HH * UU, 256, 0, stream>>>(q, k, v, mtop, out);
  }
}

// Round 10
// 170.694 us; speedup vs baseline: 5.1776x; 1.0378x over previous
//
#include <hip/hip_runtime.h>
#include <hip/hip_bf16.h>
#include <math.h>
#include <stdint.h>

// (B, L, H, D) = (4, 2048, 8, 64); FACTOR=5 => U_part = u = 40.
static constexpr int BB = 4;
static constexpr int LL = 2048;
static constexpr int HH = 8;
static constexpr int DD = 64;
static constexpr int UU = 40;
static constexpr int NSAMP = 40;
static constexpr int BHL = BB * HH * LL;       // 65536
static constexpr int ROWSTRIDE = HH * DD;      // 512
static constexpr int VCHUNKS = 64;
static constexpr int NC = 16;                  // KV chunks per (b,h)
static constexpr int CR = 128;                 // K rows per chunk
static constexpr int QS = 20;                  // queries per attn block (2 halves)
static constexpr int SCOREBLK = BHL / 4;       // 16384 blocks for scores
static constexpr int P1BLK = SCOREBLK + BB * HH * VCHUNKS;  // 18432

// ---- workspace layout (big path) ----
// phase1 out:  M @0 (262144), vpart @262144 (524288)          [dead after phase2]
// attn out:    pm @0 (81920), ps @81920 (81920), pacc @163840 (5242880) -> 5406720
// phase2 out:  mtop @5406720 (5120), vmean @5411840 (8192), tbl @5420032 (262144)
// WS_NEED = 5682176
static constexpr size_t WS_NEED = 5682176;

// ---------------- Threefry-2x32 (JAX partitionable mode) ----------------
__device__ __forceinline__ uint32_t rotl32(uint32_t x, uint32_t n) {
  return (x << n) | (x >> (32u - n));
}

__device__ __forceinline__ void tf2x32(uint32_t k0, uint32_t k1,
                                       uint32_t x0, uint32_t x1,
                                       uint32_t& o0, uint32_t& o1) {
  uint32_t ks[3] = {k0, k1, k0 ^ k1 ^ 0x1BD11BDAu};
  x0 += ks[0];
  x1 += ks[1];
  const uint32_t rotA[4] = {13u, 15u, 26u, 6u};
  const uint32_t rotB[4] = {17u, 29u, 16u, 24u};
#pragma unroll
  for (int i = 0; i < 5; ++i) {
    const uint32_t* r = (i & 1) ? rotB : rotA;
#pragma unroll
    for (int j = 0; j < 4; ++j) {
      x0 += x1;
      x1 = rotl32(x1, r[j]);
      x1 ^= x0;
    }
    x0 += ks[(i + 1) % 3];
    x1 += ks[(i + 2) % 3] + (uint32_t)(i + 1);
  }
  o0 = x0;
  o1 = x1;
}

__device__ __forceinline__ float dot4(float4 a, float4 b) {
  return a.x * b.x + a.y * b.y + a.z * b.z + a.w * b.w;
}

// ---- phase 1: scores_M (blocks 0..16383, XCD-swizzled) + vmean_part (rest) ----
__global__ void __launch_bounds__(256)
k_phase1(const float* __restrict__ q, const float* __restrict__ k,
         const float* __restrict__ v, float* __restrict__ M,
         float* __restrict__ vpart) {
  if (blockIdx.x < SCOREBLK) {
    // M[b,h,qq] = max - mean over 40 sampled dots; one wave per query.
    int wg = (blockIdx.x & 7) * (SCOREBLK / 8) + (blockIdx.x >> 3);  // bijective
    int w = wg * 4 + (threadIdx.x >> 6);
    int lane = threadIdx.x & 63;
    int qq = w & (LL - 1);
    int h = (w >> 11) & (HH - 1);
    int b = w >> 14;
    uint32_t ka, kb;
    tf2x32(0u, 42u, 0u, 1u, ka, kb);  // constant-folds
    uint32_t o0, o1;
    tf2x32(ka, kb, 0u, (uint32_t)(qq * NSAMP + lane), o0, o1);
    int idxv = (int)((o0 ^ o1) & 2047u);
    int rr = lane >> 3;  // sample slot in group of 8
    int dc = lane & 7;   // 8-float d-chunk
    const float* qrow = q + (((size_t)b * LL + qq) * HH + h) * DD;
    float4 q0 = ((const float4*)qrow)[dc * 2];
    float4 q1 = ((const float4*)qrow)[dc * 2 + 1];
    const float* kbase = k + ((size_t)b * LL * HH + h) * DD;
    int kr[5];
#pragma unroll
    for (int it = 0; it < 5; ++it) kr[it] = __shfl(idxv, it * 8 + rr);
    // batch-issue all gather loads, then reduce (one latency round-trip)
    float4 kva[5], kvb[5];
#pragma unroll
    for (int it = 0; it < 5; ++it) {
      const float4* kp = (const float4*)(kbase + (size_t)kr[it] * ROWSTRIDE);
      kva[it] = kp[dc * 2];
      kvb[it] = kp[dc * 2 + 1];
    }
    float mx = -1.0e30f, sm = 0.0f;
#pragma unroll
    for (int it = 0; it < 5; ++it) {
      float p = dot4(q0, kva[it]) + dot4(q1, kvb[it]);
      p += __shfl_xor(p, 1);
      p += __shfl_xor(p, 2);
      p += __shfl_xor(p, 4);  // reduce over dc
      mx = fmaxf(mx, p);
      sm += p;
    }
#pragma unroll
    for (int off = 8; off <= 32; off <<= 1) {  // reduce over rr
      mx = fmaxf(mx, __shfl_xor(mx, off));
      sm += __shfl_xor(sm, off);
    }
    if (lane == 0) M[w] = mx - sm * (1.0f / (float)NSAMP);
  } else {
    // vmean partial: 2048 blocks; each sums 32 rows of one (b,h).
    __shared__ float part[4][DD];
    int bid = blockIdx.x - SCOREBLK;
    int bh = bid >> 6;
    int chunk = bid & 63;
    int b = bh >> 3, h = bh & 7;
    int t = threadIdx.x;
    int wv = t >> 6, lane = t & 63;
    int l0 = chunk * (LL / VCHUNKS);
    const float* base = v + ((size_t)b * LL * HH + h) * DD + lane;
    float s = 0.0f;
#pragma unroll
    for (int r = wv; r < LL / VCHUNKS; r += 4) s += base[(size_t)(l0 + r) * ROWSTRIDE];
    part[wv][lane] = s;
    __syncthreads();
    if (t < DD) {
      vpart[(size_t)bid * DD + t] =
          (part[0][t] + part[1][t]) + (part[2][t] + part[3][t]);
    }
  }
}

// ---- phase 2: topk+tbl (blocks 0..31) + vmean_final (blocks 32..63) ----
__global__ void __launch_bounds__(256)
k_phase2(const float* __restrict__ M, const float* __restrict__ vpart,
         int* __restrict__ mtop, float* __restrict__ vmean, int* __restrict__ tbl) {
  if (blockIdx.x < BB * HH) {
    __shared__ uint32_t keys[LL];
    __shared__ int hist[256];
    __shared__ int scan_res[2];
    __shared__ int nsel, neq;
    __shared__ int sel[UU];
    __shared__ int eqlist[64];
    int bh = blockIdx.x;
    int t = threadIdx.x;
    const float* m = M + (size_t)bh * LL;
    for (int i = t; i < LL; i += 256) {
      uint32_t u = __float_as_uint(m[i]);
      keys[i] = (u & 0x80000000u) ? ~u : (u | 0x80000000u);
      tbl[bh * LL + i] = -1;
    }
    if (t == 0) { nsel = 0; neq = 0; }
    __syncthreads();

    uint32_t prefix = 0, prefmask = 0;
    int remaining = UU;
#pragma unroll
    for (int shift = 24; shift >= 0; shift -= 8) {
      hist[t] = 0;
      __syncthreads();
      for (int i = t; i < LL; i += 256) {
        uint32_t kk = keys[i];
        if ((kk & prefmask) == prefix) atomicAdd(&hist[(kk >> shift) & 0xFF], 1);
      }
      __syncthreads();
      if (t < 64) {
        int b0 = t * 4;
        int c0 = hist[b0], c1 = hist[b0 + 1], c2 = hist[b0 + 2], c3 = hist[b0 + 3];
        int g = c0 + c1 + c2 + c3;
        int s = g;
#pragma unroll
        for (int off = 1; off < 64; off <<= 1) {
          int o = __shfl_down(s, off);
          if (t + off < 64) s += o;
        }
        int a3 = s - g;
        int a2 = a3 + c3;
        int a1 = a2 + c2;
        int a0 = a1 + c1;
        if (a3 < remaining && remaining <= a3 + c3) { scan_res[0] = b0 + 3; scan_res[1] = a3; }
        if (a2 < remaining && remaining <= a2 + c2) { scan_res[0] = b0 + 2; scan_res[1] = a2; }
        if (a1 < remaining && remaining <= a1 + c1) { scan_res[0] = b0 + 1; scan_res[1] = a1; }
        if (a0 < remaining && remaining <= a0 + c0) { scan_res[0] = b0 + 0; scan_res[1] = a0; }
      }
      __syncthreads();
      prefix |= ((uint32_t)scan_res[0] << shift);
      prefmask |= (0xFFu << shift);
      remaining -= scan_res[1];
      __syncthreads();
    }

    uint32_t T = prefix;
    for (int i = t; i < LL; i += 256) {
      uint32_t kk = keys[i];
      if (kk > T) {
        int p = atomicAdd(&nsel, 1);
        sel[p] = i;
      } else if (kk == T) {
        int p = atomicAdd(&neq, 1);
        if (p < 64) eqlist[p] = i;
      }
    }
    __syncthreads();
    if (t == 0) {
      int need = UU - nsel;
      int count = neq < 64 ? neq : 64;
      for (int r = 0; r < need; ++r) {
        int mn = 1 << 30, mpos = 0;
        for (int e = 0; e < count; ++e)
          if (eqlist[e] < mn) { mn = eqlist[e]; mpos = e; }
        sel[nsel + r] = mn;
        eqlist[mpos] = 1 << 30;
      }
    }
    __syncthreads();
    if (t < UU) {
      mtop[bh * UU + t] = sel[t];
      tbl[bh * LL + sel[t]] = t;
    }
  } else {
    int bh = blockIdx.x - BB * HH;
    int d = threadIdx.x;
    if (d < DD) {
      const float* p = vpart + (size_t)bh * VCHUNKS * DD + d;
      float s = 0.0f;
#pragma unroll
      for (int c = 0; c < VCHUNKS; ++c) s += p[(size_t)c * DD];
      vmean[bh * DD + d] = s * (1.0f / (float)LL);
    }
  }
}

// ---- split-KV attention: block = (bh, q-half of 20, chunk of 128 rows) ----
__global__ void __launch_bounds__(256)
k_attn_part(const float* __restrict__ q, const float* __restrict__ k,
            const float* __restrict__ v, const int* __restrict__ mtop,
            float* __restrict__ pm, float* __restrict__ ps,
            float* __restrict__ pacc) {
  __shared__ float qs_[QS][DD];   // 5 KB
  __shared__ float sc[QS][CR];    // 10 KB
  int blk = blockIdx.x;           // bh*32 + qh*16 + c
  int c = blk & (NC - 1);
  int qh = (blk >> 4) & 1;
  int bh = blk >> 5;
  int b = bh >> 3, h = bh & 7;
  int t = threadIdx.x;
  int wv = t >> 6, lane = t & 63;
  int l0 = c * CR;
  int j0 = qh * QS;

  for (int i = t; i < QS * DD; i += 256) {
    int jj = i >> 6, d = i & 63;
    int l = mtop[bh * UU + j0 + jj];
    qs_[jj][d] = q[(((size_t)b * LL + l) * HH + h) * DD + d];
  }
  __syncthreads();

  const float* kbase = k + ((size_t)b * LL * HH + h) * DD;
  // wave holds 32 K rows: lane = (rr 16 rows, dcq 4 d-quarters of 16 floats)
  int rr = lane & 15, dcq = lane >> 4;
  float4 kv0[4], kv1[4];
  {
    const float* kr0 = kbase + (size_t)(l0 + wv * 32 + rr) * ROWSTRIDE + dcq * 16;
    const float* kr1 = kbase + (size_t)(l0 + wv * 32 + 16 + rr) * ROWSTRIDE + dcq * 16;
#pragma unroll
    for (int i = 0; i < 4; ++i) {
      kv0[i] = *(const float4*)(kr0 + i * 4);
      kv1[i] = *(const float4*)(kr1 + i * 4);
    }
  }
#pragma unroll 4
  for (int jj = 0; jj < QS; ++jj) {
    const float* qp = &qs_[jj][dcq * 16];
    float4 qa = *(const float4*)(qp);
    float4 qb = *(const float4*)(qp + 4);
    float4 qc = *(const float4*)(qp + 8);
    float4 qd = *(const float4*)(qp + 12);
    float p0 = dot4(qa, kv0[0]) + dot4(qb, kv0[1]) + dot4(qc, kv0[2]) + dot4(qd, kv0[3]);
    float p1 = dot4(qa, kv1[0]) + dot4(qb, kv1[1]) + dot4(qc, kv1[2]) + dot4(qd, kv1[3]);
    p0 += __shfl_xor(p0, 16);
    p0 += __shfl_xor(p0, 32);
    p1 += __shfl_xor(p1, 16);
    p1 += __shfl_xor(p1, 32);
    if (lane < 16) {
      sc[jj][wv * 32 + lane] = p0 * 0.125f;
      sc[jj][wv * 32 + 16 + lane] = p1 * 0.125f;
    }
  }
  __syncthreads();

  // per-query chunk softmax partials: wave owns 5 queries (jj = wv*5+u)
#pragma unroll
  for (int u = 0; u < 5; ++u) {
    int jj = wv * 5 + u;
    float a0 = sc[jj][lane];
    float a1 = sc[jj][lane + 64];
    float mx = fmaxf(a0, a1);
#pragma unroll
    for (int off = 32; off; off >>= 1) mx = fmaxf(mx, __shfl_xor(mx, off));
    float e0 = expf(a0 - mx), e1 = expf(a1 - mx);
    sc[jj][lane] = e0;
    sc[jj][lane + 64] = e1;
    float s = e0 + e1;
#pragma unroll
    for (int off = 32; off; off >>= 1) s += __shfl_xor(s, off);
    if (lane == 0) {
      pm[(size_t)(bh * NC + c) * UU + j0 + jj] = mx;
      ps[(size_t)(bh * NC + c) * UU + j0 + jj] = s;
    }
  }
  // PV: lane = d; wave's own 5 queries (sc rows written by this wave -> no barrier)
  const float* vbase = v + ((size_t)b * LL * HH + h) * DD + lane;
  float acc[5] = {0.f, 0.f, 0.f, 0.f, 0.f};
  for (int r = 0; r < CR; r += 4) {
    float v0 = vbase[(size_t)(l0 + r + 0) * ROWSTRIDE];
    float v1 = vbase[(size_t)(l0 + r + 1) * ROWSTRIDE];
    float v2 = vbase[(size_t)(l0 + r + 2) * ROWSTRIDE];
    float v3 = vbase[(size_t)(l0 + r + 3) * ROWSTRIDE];
#pragma unroll
    for (int u = 0; u < 5; ++u) {
      float4 p4 = *(const float4*)&sc[wv * 5 + u][r];
      acc[u] += p4.x * v0 + p4.y * v1 + p4.z * v2 + p4.w * v3;
    }
  }
#pragma unroll
  for (int u = 0; u < 5; ++u) {
    pacc[((size_t)(bh * NC + c) * UU + j0 + wv * 5 + u) * DD + lane] = acc[u];
  }
}

// ---- fused output: every row written once (vmean fill or 16-chunk combine) ----
__global__ void __launch_bounds__(256)
k_out(const float* __restrict__ pm, const float* __restrict__ ps,
      const float* __restrict__ pacc, const int* __restrict__ tbl,
      const float* __restrict__ vmean, float* __restrict__ out) {
  int wid = (blockIdx.x * 256 + threadIdx.x) >> 6;  // row id, 65536 total
  int lane = threadIdx.x & 63;
  int l = wid & (LL - 1);
  int bh = wid >> 11;
  int b = bh >> 3, h = bh & 7;
  int j = tbl[bh * LL + l];
  float* orow = out + (((size_t)b * LL + l) * HH + h) * DD;
  if (j < 0) {
    orow[lane] = vmean[bh * DD + lane];
  } else {
    float mv = (lane < NC) ? pm[(size_t)(bh * NC + lane) * UU + j] : -1.0e30f;
    float mx = mv;
#pragma unroll
    for (int off = 32; off; off >>= 1) mx = fmaxf(mx, __shfl_xor(mx, off));
    float e = (lane < NC) ? expf(mv - mx) : 0.0f;
    float sv = (lane < NC) ? ps[(size_t)(bh * NC + lane) * UU + j] * e : 0.0f;
    float st = sv;
#pragma unroll
    for (int off = 32; off; off >>= 1) st += __shfl_xor(st, off);
    float a = 0.0f;
#pragma unroll
    for (int c2 = 0; c2 < NC; ++c2) {
      float ec = __shfl(e, c2);
      a += ec * pacc[((size_t)(bh * NC + c2) * UU + j) * DD + lane];
    }
    orow[lane] = a / st;
  }
}

// ---- fallback small-ws path: fill + mono attention ----
__global__ void k_fill(const float* __restrict__ vmean, float* __restrict__ out) {
  int f = blockIdx.x * 256 + threadIdx.x;
  int d4 = f & 15;
  int h = (f >> 4) & 7;
  int b = f >> 18;
  ((float4*)out)[f] = ((const float4*)vmean)[(((b << 3) + h) << 4) + d4];
}

__global__ void k_attn_mono(const float* __restrict__ q, const float* __restrict__ k,
                            const float* __restrict__ v, const int* __restrict__ mtop,
                            float* __restrict__ out) {
  __shared__ float sc[LL];
  __shared__ float redm[4];
  __shared__ float reds[4];
  __shared__ float redp[4][DD];
  int blk = blockIdx.x;
  int j = blk % UU;
  int bh = blk / UU;
  int b = bh >> 3, h = bh & 7;
  int l = mtop[bh * UU + j];
  int t = threadIdx.x;
  int wv = t >> 6, lane = t & 63;
  int dc = t & 15, r2 = (t >> 4) & 3;
  const float4* qrow = (const float4*)(q + (((size_t)b * LL + l) * HH + h) * DD);
  float4 qv = qrow[dc];
  const float* kbase = k + ((size_t)b * LL * HH + h) * DD;
#pragma unroll 4
  for (int base = wv * 4; base < LL; base += 16) {
    int row = base + r2;
    const float4* krow = (const float4*)(kbase + (size_t)row * ROWSTRIDE);
    float4 kv = krow[dc];
    float p = dot4(qv, kv);
    p += __shfl_xor(p, 1);
    p += __shfl_xor(p, 2);
    p += __shfl_xor(p, 4);
    p += __shfl_xor(p, 8);
    if (dc == 0) sc[row] = p * 0.125f;
  }
  __syncthreads();
  const float4* sc4 = (const float4*)sc;
  float4 ea0 = sc4[t];
  float4 ea1 = sc4[t + 256];
  float mx = fmaxf(fmaxf(fmaxf(ea0.x, ea0.y), fmaxf(ea0.z, ea0.w)),
                   fmaxf(fmaxf(ea1.x, ea1.y), fmaxf(ea1.z, ea1.w)));
#pragma unroll
  for (int off = 32; off; off >>= 1) mx = fmaxf(mx, __shfl_xor(mx, off));
  if (lane == 0) redm[wv] = mx;
  __syncthreads();
  mx = fmaxf(fmaxf(redm[0], redm[1]), fmaxf(redm[2], redm[3]));
  ea0.x = expf(ea0.x - mx); ea0.y = expf(ea0.y - mx);
  ea0.z = expf(ea0.z - mx); ea0.w = expf(ea0.w - mx);
  ea1.x = expf(ea1.x - mx); ea1.y = expf(ea1.y - mx);
  ea1.z = expf(ea1.z - mx); ea1.w = expf(ea1.w - mx);
  float psum = ((ea0.x + ea0.y) + (ea0.z + ea0.w)) + ((ea1.x + ea1.y) + (ea1.z + ea1.w));
  float4* sc4w = (float4*)sc;
  sc4w[t] = ea0;
  sc4w[t + 256] = ea1;
#pragma unroll
  for (int off = 32; off; off >>= 1) psum += __shfl_xor(psum, off);
  if (lane == 0) reds[wv] = psum;
  __syncthreads();
  float inv = 1.0f / ((reds[0] + reds[1]) + (reds[2] + reds[3]));
  const float* vbase = v + ((size_t)b * LL * HH + h) * DD + lane;
  float acc = 0.0f;
#pragma unroll 2
  for (int base = wv * 4; base < LL; base += 16) {
    float4 p4 = sc4[base >> 2];
    acc += p4.x * vbase[(size_t)(base + 0) * ROWSTRIDE];
    acc += p4.y * vbase[(size_t)(base + 1) * ROWSTRIDE];
    acc += p4.z * vbase[(size_t)(base + 2) * ROWSTRIDE];
    acc += p4.w * vbase[(size_t)(base + 3) * ROWSTRIDE];
  }
  redp[wv][lane] = acc;
  __syncthreads();
  if (t < DD) {
    float r = (redp[0][t] + redp[1][t]) + (redp[2][t] + redp[3][t]);
    out[(((size_t)b * LL + l) * HH + h) * DD + t] = r * inv;
  }
}

extern "C" void kernel_launch(void* const* d_in, const int* in_sizes, int n_in,
                              void* d_out, int out_size, void* d_ws, size_t ws_size,
                              hipStream_t stream) {
  const float* q = (const float*)d_in[0];
  const float* k = (const float*)d_in[1];
  const float* v = (const float*)d_in[2];
  float* out = (float*)d_out;
  char* ws = (char*)d_ws;

  if (ws_size >= WS_NEED) {
    float* M = (float*)(ws);                   // dead after phase2
    float* vpart = (float*)(ws + 262144);      // dead after phase2
    float* pm = (float*)(ws);                  // written by attn (M/vpart dead)
    float* ps = (float*)(ws + 81920);
    float* pacc = (float*)(ws + 163840);       // ends 5406720
    int* mtop = (int*)(ws + 5406720);
    float* vmean = (float*)(ws + 5411840);
    int* tbl = (int*)(ws + 5420032);           // ends 5682176

    k_phase1<<<P1BLK, 256, 0, stream>>>(q, k, v, M, vpart);
    k_phase2<<<2 * BB * HH, 256, 0, stream>>>(M, vpart, mtop, vmean, tbl);
    k_attn_part<<<BB * HH * NC * 2, 256, 0, stream>>>(q, k, v, mtop, pm, ps, pacc);
    k_out<<<BHL / 4, 256, 0, stream>>>(pm, ps, pacc, tbl, vmean, out);
  } else {
    float* M = (float*)(ws);                   // 262144; tbl aliases M (safe: topk
    int* tbl = (int*)(ws);                     //  stages M to LDS before tbl writes)
    float* vpart = (float*)(ws + 262144);      // 524288
    int* mtop = (int*)(ws + 786432);           // 5120
    float* vmean = (float*)(ws + 791552);      // 8192 -> 799744

    k_phase1<<<P1BLK, 256, 0, stream>>>(q, k, v, M, vpart);
    k_phase2<<<2 * BB * HH, 256, 0, stream>>>(M, vpart, mtop, vmean, tbl);
    k_fill<<<(BB * LL * HH * DD / 4) / 256, 256, 0, stream>>>(vmean, out);
    k_attn_mono<<<BB * HH * UU, 256, 0, stream>>>(q, k, v, mtop, out);
  }
}

// Round 11
// 165.797 us; speedup vs baseline: 5.3305x; 1.0295x over previous
//
#include <hip/hip_runtime.h>
#include <hip/hip_bf16.h>
#include <math.h>
#include <stdint.h>

// (B, L, H, D) = (4, 2048, 8, 64); FACTOR=5 => U_part = u = 40.
static constexpr int BB = 4;
static constexpr int LL = 2048;
static constexpr int HH = 8;
static constexpr int DD = 64;
static constexpr int UU = 40;
static constexpr int NSAMP = 40;
static constexpr int BHL = BB * HH * LL;       // 65536
static constexpr int NIDX = LL * NSAMP;        // 81920
static constexpr int ROWSTRIDE = HH * DD;      // 512
static constexpr int VCHUNKS = 64;
static constexpr int NC = 16;                  // KV chunks per (b,h)
static constexpr int CR = 128;                 // K rows per chunk
static constexpr int QS = 20;                  // queries per attn block (2 halves)
static constexpr int SCOREBLK = BHL / 4;       // 16384
static constexpr int IDXBLK = NIDX / 256;      // 320
static constexpr int PREBLK = IDXBLK + BB * HH * VCHUNKS;  // 2368

// ---- workspace layout (big path) ----
// idx @0 (327680)                       [k_pre .. k_scores]
// vpart @327680 (524288)                [k_pre .. k_phase2]
// M @851968 (262144)                    [k_scores .. k_phase2]
// pm @0 (81920), ps @81920 (81920)      [attn ..]  (idx dead)
// pacc @163840 (5242880) -> 5406720     [attn ..]  (vpart/M dead)
// mtop @5406720 (5120), vmean @5411840 (8192), tbl @5420032 (262144)
// WS_NEED = 5682176  (same as R10, known to fit)
static constexpr size_t WS_NEED = 5682176;

// ---------------- Threefry-2x32 (JAX partitionable mode) ----------------
__device__ __forceinline__ uint32_t rotl32(uint32_t x, uint32_t n) {
  return (x << n) | (x >> (32u - n));
}

__device__ __forceinline__ void tf2x32(uint32_t k0, uint32_t k1,
                                       uint32_t x0, uint32_t x1,
                                       uint32_t& o0, uint32_t& o1) {
  uint32_t ks[3] = {k0, k1, k0 ^ k1 ^ 0x1BD11BDAu};
  x0 += ks[0];
  x1 += ks[1];
  const uint32_t rotA[4] = {13u, 15u, 26u, 6u};
  const uint32_t rotB[4] = {17u, 29u, 16u, 24u};
#pragma unroll
  for (int i = 0; i < 5; ++i) {
    const uint32_t* r = (i & 1) ? rotB : rotA;
#pragma unroll
    for (int j = 0; j < 4; ++j) {
      x0 += x1;
      x1 = rotl32(x1, r[j]);
      x1 ^= x0;
    }
    x0 += ks[(i + 1) % 3];
    x1 += ks[(i + 2) % 3] + (uint32_t)(i + 1);
  }
  o0 = x0;
  o1 = x1;
}

__device__ __forceinline__ float dot4(float4 a, float4 b) {
  return a.x * b.x + a.y * b.y + a.z * b.z + a.w * b.w;
}

// ---- k_pre: build idx table (blocks 0..319) + vmean partials (rest) ----
__global__ void __launch_bounds__(256)
k_pre(const float* __restrict__ v, int* __restrict__ idx, float* __restrict__ vpart) {
  if (blockIdx.x < IDXBLK) {
    int i = blockIdx.x * 256 + threadIdx.x;  // < 81920 exactly
    uint32_t ka, kb;
    tf2x32(0u, 42u, 0u, 1u, ka, kb);  // split(key(42)) -> second subkey (folds)
    uint32_t o0, o1;
    tf2x32(ka, kb, 0u, (uint32_t)i, o0, o1);
    idx[i] = (int)((o0 ^ o1) & 2047u);  // partitionable random_bits: o0^o1
  } else {
    __shared__ float part[4][DD];
    int bid = blockIdx.x - IDXBLK;
    int bh = bid >> 6;
    int chunk = bid & 63;
    int b = bh >> 3, h = bh & 7;
    int t = threadIdx.x;
    int wv = t >> 6, lane = t & 63;
    int l0 = chunk * (LL / VCHUNKS);
    const float* base = v + ((size_t)b * LL * HH + h) * DD + lane;
    float s = 0.0f;
#pragma unroll
    for (int r = wv; r < LL / VCHUNKS; r += 4) s += base[(size_t)(l0 + r) * ROWSTRIDE];
    part[wv][lane] = s;
    __syncthreads();
    if (t < DD) {
      vpart[(size_t)bid * DD + t] =
          (part[0][t] + part[1][t]) + (part[2][t] + part[3][t]);
    }
  }
}

// ---- k_scores: M = max-mean over 40 sampled dots; one wave per (b,h,q) ----
__global__ void __launch_bounds__(256)
k_scores(const float* __restrict__ q, const float* __restrict__ k,
         const int* __restrict__ idx, float* __restrict__ M) {
  int wg = (blockIdx.x & 7) * (SCOREBLK / 8) + (blockIdx.x >> 3);  // XCD swizzle
  int w = wg * 4 + (threadIdx.x >> 6);
  int lane = threadIdx.x & 63;
  int qq = w & (LL - 1);
  int h = (w >> 11) & (HH - 1);
  int b = w >> 14;
  int idxv = (lane < NSAMP) ? idx[qq * NSAMP + lane] : 0;
  int rr = lane >> 3;  // sample slot in group of 8
  int dc = lane & 7;   // 8-float d-chunk
  const float* qrow = q + (((size_t)b * LL + qq) * HH + h) * DD;
  float4 q0 = ((const float4*)qrow)[dc * 2];
  float4 q1 = ((const float4*)qrow)[dc * 2 + 1];
  const float* kbase = k + ((size_t)b * LL * HH + h) * DD;
  int kr[5];
#pragma unroll
  for (int it = 0; it < 5; ++it) kr[it] = __shfl(idxv, it * 8 + rr);
  float4 kva[5], kvb[5];
#pragma unroll
  for (int it = 0; it < 5; ++it) {
    const float4* kp = (const float4*)(kbase + (size_t)kr[it] * ROWSTRIDE);
    kva[it] = kp[dc * 2];
    kvb[it] = kp[dc * 2 + 1];
  }
  float mx = -1.0e30f, sm = 0.0f;
#pragma unroll
  for (int it = 0; it < 5; ++it) {
    float p = dot4(q0, kva[it]) + dot4(q1, kvb[it]);
    p += __shfl_xor(p, 1);
    p += __shfl_xor(p, 2);
    p += __shfl_xor(p, 4);  // reduce over dc
    mx = fmaxf(mx, p);
    sm += p;
  }
#pragma unroll
  for (int off = 8; off <= 32; off <<= 1) {  // reduce over rr
    mx = fmaxf(mx, __shfl_xor(mx, off));
    sm += __shfl_xor(sm, off);
  }
  if (lane == 0) M[w] = mx - sm * (1.0f / (float)NSAMP);
}

// ---- phase 2: topk+tbl (blocks 0..31) + vmean_final (blocks 32..63) ----
__global__ void __launch_bounds__(256)
k_phase2(const float* __restrict__ M, const float* __restrict__ vpart,
         int* __restrict__ mtop, float* __restrict__ vmean, int* __restrict__ tbl) {
  if (blockIdx.x < BB * HH) {
    __shared__ uint32_t keys[LL];
    __shared__ int hist[256];
    __shared__ int scan_res[2];
    __shared__ int nsel, neq;
    __shared__ int sel[UU];
    __shared__ int eqlist[64];
    int bh = blockIdx.x;
    int t = threadIdx.x;
    const float* m = M + (size_t)bh * LL;
    for (int i = t; i < LL; i += 256) {
      uint32_t u = __float_as_uint(m[i]);
      keys[i] = (u & 0x80000000u) ? ~u : (u | 0x80000000u);
      tbl[bh * LL + i] = -1;
    }
    if (t == 0) { nsel = 0; neq = 0; }
    __syncthreads();

    uint32_t prefix = 0, prefmask = 0;
    int remaining = UU;
#pragma unroll
    for (int shift = 24; shift >= 0; shift -= 8) {
      hist[t] = 0;
      __syncthreads();
      for (int i = t; i < LL; i += 256) {
        uint32_t kk = keys[i];
        if ((kk & prefmask) == prefix) atomicAdd(&hist[(kk >> shift) & 0xFF], 1);
      }
      __syncthreads();
      if (t < 64) {
        int b0 = t * 4;
        int c0 = hist[b0], c1 = hist[b0 + 1], c2 = hist[b0 + 2], c3 = hist[b0 + 3];
        int g = c0 + c1 + c2 + c3;
        int s = g;
#pragma unroll
        for (int off = 1; off < 64; off <<= 1) {
          int o = __shfl_down(s, off);
          if (t + off < 64) s += o;
        }
        int a3 = s - g;
        int a2 = a3 + c3;
        int a1 = a2 + c2;
        int a0 = a1 + c1;
        if (a3 < remaining && remaining <= a3 + c3) { scan_res[0] = b0 + 3; scan_res[1] = a3; }
        if (a2 < remaining && remaining <= a2 + c2) { scan_res[0] = b0 + 2; scan_res[1] = a2; }
        if (a1 < remaining && remaining <= a1 + c1) { scan_res[0] = b0 + 1; scan_res[1] = a1; }
        if (a0 < remaining && remaining <= a0 + c0) { scan_res[0] = b0 + 0; scan_res[1] = a0; }
      }
      __syncthreads();
      prefix |= ((uint32_t)scan_res[0] << shift);
      prefmask |= (0xFFu << shift);
      remaining -= scan_res[1];
      __syncthreads();
    }

    uint32_t T = prefix;
    for (int i = t; i < LL; i += 256) {
      uint32_t kk = keys[i];
      if (kk > T) {
        int p = atomicAdd(&nsel, 1);
        sel[p] = i;
      } else if (kk == T) {
        int p = atomicAdd(&neq, 1);
        if (p < 64) eqlist[p] = i;
      }
    }
    __syncthreads();
    if (t == 0) {
      int need = UU - nsel;
      int count = neq < 64 ? neq : 64;
      for (int r = 0; r < need; ++r) {
        int mn = 1 << 30, mpos = 0;
        for (int e = 0; e < count; ++e)
          if (eqlist[e] < mn) { mn = eqlist[e]; mpos = e; }
        sel[nsel + r] = mn;
        eqlist[mpos] = 1 << 30;
      }
    }
    __syncthreads();
    if (t < UU) {
      mtop[bh * UU + t] = sel[t];
      tbl[bh * LL + sel[t]] = t;
    }
  } else {
    int bh = blockIdx.x - BB * HH;
    int d = threadIdx.x;
    if (d < DD) {
      const float* p = vpart + (size_t)bh * VCHUNKS * DD + d;
      float s = 0.0f;
#pragma unroll
      for (int c = 0; c < VCHUNKS; ++c) s += p[(size_t)c * DD];
      vmean[bh * DD + d] = s * (1.0f / (float)LL);
    }
  }
}

// ---- split-KV attention: block = (bh, q-half of 20, chunk of 128 rows) ----
// PV: each wave covers a 32-row strip for ALL 20 queries (V read once/block),
// then LDS-combine to the 128-row chunk partial.
__global__ void __launch_bounds__(256)
k_attn_part(const float* __restrict__ q, const float* __restrict__ k,
            const float* __restrict__ v, const int* __restrict__ mtop,
            float* __restrict__ pm, float* __restrict__ ps,
            float* __restrict__ pacc) {
  __shared__ float qs_[QS][DD];        // 5 KB
  __shared__ float sc[QS][CR];         // 10 KB
  __shared__ float pl[4][QS][DD];      // 20 KB
  int blk = blockIdx.x;                // bh*32 + qh*16 + c
  int c = blk & (NC - 1);
  int qh = (blk >> 4) & 1;
  int bh = blk >> 5;
  int b = bh >> 3, h = bh & 7;
  int t = threadIdx.x;
  int wv = t >> 6, lane = t & 63;
  int l0 = c * CR;
  int j0 = qh * QS;

  for (int i = t; i < QS * DD; i += 256) {
    int jj = i >> 6, d = i & 63;
    int l = mtop[bh * UU + j0 + jj];
    qs_[jj][d] = q[(((size_t)b * LL + l) * HH + h) * DD + d];
  }
  __syncthreads();

  const float* kbase = k + ((size_t)b * LL * HH + h) * DD;
  // wave holds 32 K rows: lane = (rr 16 rows, dcq 4 d-quarters of 16 floats)
  int rr = lane & 15, dcq = lane >> 4;
  float4 kv0[4], kv1[4];
  {
    const float* kr0 = kbase + (size_t)(l0 + wv * 32 + rr) * ROWSTRIDE + dcq * 16;
    const float* kr1 = kbase + (size_t)(l0 + wv * 32 + 16 + rr) * ROWSTRIDE + dcq * 16;
#pragma unroll
    for (int i = 0; i < 4; ++i) {
      kv0[i] = *(const float4*)(kr0 + i * 4);
      kv1[i] = *(const float4*)(kr1 + i * 4);
    }
  }
#pragma unroll 4
  for (int jj = 0; jj < QS; ++jj) {
    const float* qp = &qs_[jj][dcq * 16];
    float4 qa = *(const float4*)(qp);
    float4 qb = *(const float4*)(qp + 4);
    float4 qc = *(const float4*)(qp + 8);
    float4 qd = *(const float4*)(qp + 12);
    float p0 = dot4(qa, kv0[0]) + dot4(qb, kv0[1]) + dot4(qc, kv0[2]) + dot4(qd, kv0[3]);
    float p1 = dot4(qa, kv1[0]) + dot4(qb, kv1[1]) + dot4(qc, kv1[2]) + dot4(qd, kv1[3]);
    p0 += __shfl_xor(p0, 16);
    p0 += __shfl_xor(p0, 32);
    p1 += __shfl_xor(p1, 16);
    p1 += __shfl_xor(p1, 32);
    if (lane < 16) {
      sc[jj][wv * 32 + lane] = p0 * 0.125f;
      sc[jj][wv * 32 + 16 + lane] = p1 * 0.125f;
    }
  }
  __syncthreads();

  // per-query chunk softmax partials: wave owns 5 queries (jj = wv*5+u)
#pragma unroll
  for (int u = 0; u < 5; ++u) {
    int jj = wv * 5 + u;
    float a0 = sc[jj][lane];
    float a1 = sc[jj][lane + 64];
    float mx = fmaxf(a0, a1);
#pragma unroll
    for (int off = 32; off; off >>= 1) mx = fmaxf(mx, __shfl_xor(mx, off));
    float e0 = expf(a0 - mx), e1 = expf(a1 - mx);
    sc[jj][lane] = e0;
    sc[jj][lane + 64] = e1;
    float s = e0 + e1;
#pragma unroll
    for (int off = 32; off; off >>= 1) s += __shfl_xor(s, off);
    if (lane == 0) {
      pm[(size_t)(bh * NC + c) * UU + j0 + jj] = mx;
      ps[(size_t)(bh * NC + c) * UU + j0 + jj] = s;
    }
  }
  __syncthreads();  // all e-values visible to all waves

  // PV: wave strip = rows [wv*32, wv*32+32), all 20 queries; lane = d
  const float* vbase = v + ((size_t)b * LL * HH + h) * DD + lane;
  float acc[QS];
#pragma unroll
  for (int u = 0; u < QS; ++u) acc[u] = 0.0f;
  for (int r = wv * 32; r < wv * 32 + 32; r += 4) {
    float v0 = vbase[(size_t)(l0 + r + 0) * ROWSTRIDE];
    float v1 = vbase[(size_t)(l0 + r + 1) * ROWSTRIDE];
    float v2 = vbase[(size_t)(l0 + r + 2) * ROWSTRIDE];
    float v3 = vbase[(size_t)(l0 + r + 3) * ROWSTRIDE];
#pragma unroll
    for (int u = 0; u < QS; ++u) {
      float4 p4 = *(const float4*)&sc[u][r];  // wave-uniform broadcast
      acc[u] += p4.x * v0 + p4.y * v1 + p4.z * v2 + p4.w * v3;
    }
  }
#pragma unroll
  for (int u = 0; u < QS; ++u) pl[wv][u][lane] = acc[u];
  __syncthreads();
  // each wave writes its 5 owned queries (sum of 4 strips)
#pragma unroll
  for (int u = 0; u < 5; ++u) {
    int jj = wv * 5 + u;
    float r = (pl[0][jj][lane] + pl[1][jj][lane]) + (pl[2][jj][lane] + pl[3][jj][lane]);
    pacc[((size_t)(bh * NC + c) * UU + j0 + jj) * DD + lane] = r;
  }
}

// ---- fused output: every row written once (vmean fill or 16-chunk combine) ----
__global__ void __launch_bounds__(256)
k_out(const float* __restrict__ pm, const float* __restrict__ ps,
      const float* __restrict__ pacc, const int* __restrict__ tbl,
      const float* __restrict__ vmean, float* __restrict__ out) {
  int wid = (blockIdx.x * 256 + threadIdx.x) >> 6;  // row id, 65536 total
  int lane = threadIdx.x & 63;
  int l = wid & (LL - 1);
  int bh = wid >> 11;
  int b = bh >> 3, h = bh & 7;
  int j = tbl[bh * LL + l];
  float* orow = out + (((size_t)b * LL + l) * HH + h) * DD;
  if (j < 0) {
    orow[lane] = vmean[bh * DD + lane];
  } else {
    float mv = (lane < NC) ? pm[(size_t)(bh * NC + lane) * UU + j] : -1.0e30f;
    float mx = mv;
#pragma unroll
    for (int off = 32; off; off >>= 1) mx = fmaxf(mx, __shfl_xor(mx, off));
    float e = (lane < NC) ? expf(mv - mx) : 0.0f;
    float sv = (lane < NC) ? ps[(size_t)(bh * NC + lane) * UU + j] * e : 0.0f;
    float st = sv;
#pragma unroll
    for (int off = 32; off; off >>= 1) st += __shfl_xor(st, off);
    float a = 0.0f;
#pragma unroll
    for (int c2 = 0; c2 < NC; ++c2) {
      float ec = __shfl(e, c2);
      a += ec * pacc[((size_t)(bh * NC + c2) * UU + j) * DD + lane];
    }
    orow[lane] = a / st;
  }
}

// ---- fallback small-ws path: fill + mono attention ----
__global__ void k_fill(const float* __restrict__ vmean, float* __restrict__ out) {
  int f = blockIdx.x * 256 + threadIdx.x;
  int d4 = f & 15;
  int h = (f >> 4) & 7;
  int b = f >> 18;
  ((float4*)out)[f] = ((const float4*)vmean)[(((b << 3) + h) << 4) + d4];
}

__global__ void k_attn_mono(const float* __restrict__ q, const float* __restrict__ k,
                            const float* __restrict__ v, const int* __restrict__ mtop,
                            float* __restrict__ out) {
  __shared__ float sc[LL];
  __shared__ float redm[4];
  __shared__ float reds[4];
  __shared__ float redp[4][DD];
  int blk = blockIdx.x;
  int j = blk % UU;
  int bh = blk / UU;
  int b = bh >> 3, h = bh & 7;
  int l = mtop[bh * UU + j];
  int t = threadIdx.x;
  int wv = t >> 6, lane = t & 63;
  int dc = t & 15, r2 = (t >> 4) & 3;
  const float4* qrow = (const float4*)(q + (((size_t)b * LL + l) * HH + h) * DD);
  float4 qv = qrow[dc];
  const float* kbase = k + ((size_t)b * LL * HH + h) * DD;
#pragma unroll 4
  for (int base = wv * 4; base < LL; base += 16) {
    int row = base + r2;
    const float4* krow = (const float4*)(kbase + (size_t)row * ROWSTRIDE);
    float4 kv = krow[dc];
    float p = dot4(qv, kv);
    p += __shfl_xor(p, 1);
    p += __shfl_xor(p, 2);
    p += __shfl_xor(p, 4);
    p += __shfl_xor(p, 8);
    if (dc == 0) sc[row] = p * 0.125f;
  }
  __syncthreads();
  const float4* sc4 = (const float4*)sc;
  float4 ea0 = sc4[t];
  float4 ea1 = sc4[t + 256];
  float mx = fmaxf(fmaxf(fmaxf(ea0.x, ea0.y), fmaxf(ea0.z, ea0.w)),
                   fmaxf(fmaxf(ea1.x, ea1.y), fmaxf(ea1.z, ea1.w)));
#pragma unroll
  for (int off = 32; off; off >>= 1) mx = fmaxf(mx, __shfl_xor(mx, off));
  if (lane == 0) redm[wv] = mx;
  __syncthreads();
  mx = fmaxf(fmaxf(redm[0], redm[1]), fmaxf(redm[2], redm[3]));
  ea0.x = expf(ea0.x - mx); ea0.y = expf(ea0.y - mx);
  ea0.z = expf(ea0.z - mx); ea0.w = expf(ea0.w - mx);
  ea1.x = expf(ea1.x - mx); ea1.y = expf(ea1.y - mx);
  ea1.z = expf(ea1.z - mx); ea1.w = expf(ea1.w - mx);
  float psum = ((ea0.x + ea0.y) + (ea0.z + ea0.w)) + ((ea1.x + ea1.y) + (ea1.z + ea1.w));
  float4* sc4w = (float4*)sc;
  sc4w[t] = ea0;
  sc4w[t + 256] = ea1;
#pragma unroll
  for (int off = 32; off; off >>= 1) psum += __shfl_xor(psum, off);
  if (lane == 0) reds[wv] = psum;
  __syncthreads();
  float inv = 1.0f / ((reds[0] + reds[1]) + (reds[2] + reds[3]));
  const float* vbase = v + ((size_t)b * LL * HH + h) * DD + lane;
  float acc = 0.0f;
#pragma unroll 2
  for (int base = wv * 4; base < LL; base += 16) {
    float4 p4 = sc4[base >> 2];
    acc += p4.x * vbase[(size_t)(base + 0) * ROWSTRIDE];
    acc += p4.y * vbase[(size_t)(base + 1) * ROWSTRIDE];
    acc += p4.z * vbase[(size_t)(base + 2) * ROWSTRIDE];
    acc += p4.w * vbase[(size_t)(base + 3) * ROWSTRIDE];
  }
  redp[wv][lane] = acc;
  __syncthreads();
  if (t < DD) {
    float r = (redp[0][t] + redp[1][t]) + (redp[2][t] + redp[3][t]);
    out[(((size_t)b * LL + l) * HH + h) * DD + t] = r * inv;
  }
}

extern "C" void kernel_launch(void* const* d_in, const int* in_sizes, int n_in,
                              void* d_out, int out_size, void* d_ws, size_t ws_size,
                              hipStream_t stream) {
  const float* q = (const float*)d_in[0];
  const float* k = (const float*)d_in[1];
  const float* v = (const float*)d_in[2];
  float* out = (float*)d_out;
  char* ws = (char*)d_ws;

  if (ws_size >= WS_NEED) {
    int* idx = (int*)(ws);                     // dead after k_scores
    float* vpart = (float*)(ws + 327680);      // dead after k_phase2
    float* M = (float*)(ws + 851968);          // dead after k_phase2
    float* pm = (float*)(ws);                  // attn writes (idx dead)
    float* ps = (float*)(ws + 81920);
    float* pacc = (float*)(ws + 163840);       // attn writes (vpart/M dead)
    int* mtop = (int*)(ws + 5406720);
    float* vmean = (float*)(ws + 5411840);
    int* tbl = (int*)(ws + 5420032);           // ends 5682176

    k_pre<<<PREBLK, 256, 0, stream>>>(v, idx, vpart);
    k_scores<<<SCOREBLK, 256, 0, stream>>>(q, k, idx, M);
    k_phase2<<<2 * BB * HH, 256, 0, stream>>>(M, vpart, mtop, vmean, tbl);
    k_attn_part<<<BB * HH * NC * 2, 256, 0, stream>>>(q, k, v, mtop, pm, ps, pacc);
    k_out<<<BHL / 4, 256, 0, stream>>>(pm, ps, pacc, tbl, vmean, out);
  } else {
    int* idx = (int*)(ws);                     // 327680
    float* vpart = (float*)(ws + 327680);      // 524288
    float* M = (float*)(ws + 851968);          // 262144 -> 1114112
    int* mtop = (int*)(ws + 1114112);          // 5120
    float* vmean = (float*)(ws + 1119232);     // 8192
    int* tbl = (int*)(ws + 1127424);           // 262144 -> 1389568

    k_pre<<<PREBLK, 256, 0, stream>>>(v, idx, vpart);
    k_scores<<<SCOREBLK, 256, 0, stream>>>(q, k, idx, M);
    k_phase2<<<2 * BB * HH, 256, 0, stream>>>(M, vpart, mtop, vmean, tbl);
    k_fill<<<(BB * LL * HH * DD / 4) / 256, 256, 0, stream>>>(vmean, out);
    k_attn_mono<<<BB * HH * UU, 256, 0, stream>>>(q, k, v, mtop, out);
  }
}